// Round 3
// baseline (3704.024 us; speedup 1.0000x reference)
//
#include <hip/hip_runtime.h>
#include <math.h>

#define BATCH 32
#define SEQT 384
#define DIM 768
#define D3 2304
#define NROWS (BATCH*SEQT)      // 12288
#define VTHRESH 0.95f

typedef float  f32x4 __attribute__((ext_vector_type(4)));

// ---------------- workspace layout (bytes) ----------------
#define OFF_XP   ((size_t)0)
#define SZ_XP    ((size_t)NROWS * D3 * 4)            // 113,246,208
#define OFF_ST   (OFF_XP + SZ_XP)
#define SZ_ST    ((size_t)NROWS * DIM * 4)           // 37,748,736
#define OFF_PR   (OFF_ST + SZ_ST)
#define SZ_PR    ((size_t)NROWS * 4)
#define OFF_WT   (OFF_PR + SZ_PR)
#define OFF_SS   (OFF_WT + SZ_PR)
#define OFF_SE   (OFF_SS + SZ_PR)
#define OFF_NS   (OFF_SE + SZ_PR)
#define OFF_HB   (OFF_NS + 256)
// hbuf: 2 parity x 8 bg x 768 cols x 2 chunks x 16B = 393,216 B
#define NBG 8               // batch groups (4 batches each)
#define BPG 4               // batches per group
#define HCH 2               // 16B chunks per column (s0: b0..b2+tag, s1: b3+tag)
#define BGBYTES ((size_t)(DIM * HCH * 16))   // 24,576
#define SZ_HB   ((size_t)2 * NBG * BGBYTES)  // 393,216

#define DOT4(a,b) ((a).x*(b).x + (a).y*(b).y + (a).z*(b).z + (a).w*(b).w)

// =========================================================
// K1: xp[m][n] = sum_k emb[sent[m]][k] * w_ih[n][k] + b_ih[n]
// =========================================================
__global__ __launch_bounds__(256, 2) void k_xp(
    const int* __restrict__ sent, const float* __restrict__ emb,
    const float* __restrict__ w_ih, const float* __restrict__ b_ih,
    float* __restrict__ xp)
{
    __shared__ float As[16][132];
    __shared__ float Bs[16][132];
    const int tid = threadIdx.x;
    const int mt = blockIdx.x, nt = blockIdx.y;
    const int tx = tid & 15, ty = tid >> 4;
    const int lm = tid >> 2;          // 0..63
    const int lk = (tid & 3) << 2;    // 0,4,8,12

    const long arow0 = (long)sent[mt*128 + lm] * DIM;
    const long arow1 = (long)sent[mt*128 + lm + 64] * DIM;
    const float* b0p = w_ih + (size_t)(nt*128 + lm) * DIM;
    const float* b1p = w_ih + (size_t)(nt*128 + lm + 64) * DIM;

    float acc[8][8];
    #pragma unroll
    for (int i = 0; i < 8; ++i)
        #pragma unroll
        for (int j = 0; j < 8; ++j) acc[i][j] = 0.f;

    for (int k0 = 0; k0 < DIM; k0 += 16) {
        float4 a0 = *(const float4*)(emb + arow0 + k0 + lk);
        float4 a1 = *(const float4*)(emb + arow1 + k0 + lk);
        float4 b0 = *(const float4*)(b0p + k0 + lk);
        float4 b1 = *(const float4*)(b1p + k0 + lk);
        __syncthreads();
        As[lk+0][lm] = a0.x; As[lk+1][lm] = a0.y; As[lk+2][lm] = a0.z; As[lk+3][lm] = a0.w;
        As[lk+0][lm+64] = a1.x; As[lk+1][lm+64] = a1.y; As[lk+2][lm+64] = a1.z; As[lk+3][lm+64] = a1.w;
        Bs[lk+0][lm] = b0.x; Bs[lk+1][lm] = b0.y; Bs[lk+2][lm] = b0.z; Bs[lk+3][lm] = b0.w;
        Bs[lk+0][lm+64] = b1.x; Bs[lk+1][lm+64] = b1.y; Bs[lk+2][lm+64] = b1.z; Bs[lk+3][lm+64] = b1.w;
        __syncthreads();
        #pragma unroll
        for (int k = 0; k < 16; ++k) {
            float4 av0 = *(const float4*)&As[k][ty*8];
            float4 av1 = *(const float4*)&As[k][ty*8+4];
            float4 bv0 = *(const float4*)&Bs[k][tx*8];
            float4 bv1 = *(const float4*)&Bs[k][tx*8+4];
            float a[8] = {av0.x,av0.y,av0.z,av0.w,av1.x,av1.y,av1.z,av1.w};
            float b[8] = {bv0.x,bv0.y,bv0.z,bv0.w,bv1.x,bv1.y,bv1.z,bv1.w};
            #pragma unroll
            for (int i = 0; i < 8; ++i)
                #pragma unroll
                for (int j = 0; j < 8; ++j)
                    acc[i][j] += a[i]*b[j];
        }
    }

    const int m0 = mt*128 + ty*8;
    const int n0 = nt*128 + tx*8;
    float4 bi0 = *(const float4*)(b_ih + n0);
    float4 bi1 = *(const float4*)(b_ih + n0 + 4);
    #pragma unroll
    for (int i = 0; i < 8; ++i) {
        float4 v0, v1;
        v0.x = acc[i][0] + bi0.x; v0.y = acc[i][1] + bi0.y;
        v0.z = acc[i][2] + bi0.z; v0.w = acc[i][3] + bi0.w;
        v1.x = acc[i][4] + bi1.x; v1.y = acc[i][5] + bi1.y;
        v1.z = acc[i][6] + bi1.z; v1.w = acc[i][7] + bi1.w;
        *(float4*)(xp + (size_t)(m0+i)*D3 + n0)     = v0;
        *(float4*)(xp + (size_t)(m0+i)*D3 + n0 + 4) = v1;
    }
}

// =========================================================
// K2: persistent GRU recurrence, v7 — occupancy-first.
//   R2 post-mortem: v6's "pipeline" ran both phases in the SAME waves,
//   so WAIT stalls still blocked issue; VALUBusy math showed we're 2x
//   from VALU-issue-bound with 52% idle = unfillable wait (1 WG/CU).
//   v7: 8 bg x 4 batches x 64 WGs = 512 WGs -> 2 WGs/CU (12 waves).
//   One WG's poll-wait overlaps the sibling WG's compute at the SIMD
//   scheduler (m114). Plus VALU trim:
//   - 12 contiguous cols/WG: xp sector overfetch 2.7x -> 1.3x.
//   - 4 poll chunks/thread (was 6); chunk = [b0,b1,b2,tag]/[b3,-,-,tag].
//   - reduce strictly within 32 lanes (ds_swizzle; no xor-32 bpermute).
//   - publish via 4 shfls, wave-local (no out_lds, no extra barrier).
//   - h_lds double-buffered -> exactly ONE __syncthreads per step.
//   __launch_bounds__(384,3) caps VGPR<=170 so 2 WGs/CU are guaranteed
//   resident -> all 512 WGs co-resident (tag protocol needs this).
// =========================================================
#define HPITCH 772

__global__ __launch_bounds__(384, 3) void k_gru(
    const float* __restrict__ w_hh, const float* __restrict__ b_hh,
    const float* __restrict__ xp, float* __restrict__ states,
    char* __restrict__ hbuf)
{
    __shared__ float h_lds[2][BPG][HPITCH];   // 24,704 B

    const int tid = threadIdx.x;
    const int jb  = blockIdx.x & 63;      // WG within bg
    const int bg  = blockIdx.x >> 6;      // 0..7
    const int j    = tid >> 6;            // wave 0..5
    const int lane = tid & 63;
    const int c    = lane & 31;
    const int bh   = lane >> 5;           // which of the wave's 2 cols
    const int col  = jb*12 + j*2 + bh;
    const int bloc = ((c >> 4) & 1)*2 + ((c >> 3) & 1);  // batch-in-group
    const int batch = bg*BPG + bloc;

    // weights: gate g, k-slice {c*4 + m*128}, for this lane's col
    float4 w4[3][6];
    #pragma unroll
    for (int g3 = 0; g3 < 3; ++g3) {
        const float* wr = w_hh + (size_t)(g3*DIM + col)*DIM + c*4;
        #pragma unroll
        for (int m = 0; m < 6; ++m)
            w4[g3][m] = *(const float4*)(wr + m*128);
    }
    const float bhr = b_hh[col];
    const float bhz = b_hh[DIM + col];
    const float bhn = b_hh[2*DIM + col];

    // poll assignment: chunk q = i*384 + tid; col_q = q>>1, s_q = q&1
    int goff[4], ldsoff[4], onemask = 0;
    #pragma unroll
    for (int i = 0; i < 4; ++i) {
        int q = i*384 + tid;
        int cq = q >> 1, sq = q & 1;
        goff[i]   = q << 4;
        ldsoff[i] = 3*sq*HPITCH + cq;   // h_lds[.][3*sq + {0,1,2}][col_q]
        if (sq) onemask |= (1<<i);      // s=1 carries only 1 value
    }

    char* pb[2];
    pb[0] = hbuf + (size_t)(0*NBG + bg)*BGBYTES;
    pb[1] = hbuf + (size_t)(1*NBG + bg)*BGBYTES;

    const float* xq = xp + (size_t)batch*SEQT*D3 + col;

    f32x4 ch[4];

#define ISSUE_POLLS(pbx)                                                 \
    {                                                                    \
        _Pragma("unroll")                                                \
        for (int k = 0; k < 4; ++k) {                                    \
            const f32x4* ap = (const f32x4*)((pbx) + goff[k]);           \
            asm volatile("global_load_dwordx4 %0, %1, off sc0 sc1"       \
                         : "=v"(ch[k]) : "v"(ap));                       \
        }                                                                \
    }

#define WAIT_FILL(pbx, hb0, tt)                                          \
    {                                                                    \
        asm volatile("s_waitcnt vmcnt(0)" ::: "memory");                 \
        __builtin_amdgcn_sched_barrier(0);                               \
        int need = 15;                                                   \
        _Pragma("unroll")                                                \
        for (int k = 0; k < 4; ++k)                                      \
            if (__float_as_int(ch[k].w) == (tt)) need &= ~(1<<k);        \
        while (need) {                                                   \
            _Pragma("unroll")                                            \
            for (int k = 0; k < 4; ++k)                                  \
                if (need & (1<<k)) {                                     \
                    const f32x4* ap = (const f32x4*)((pbx) + goff[k]);   \
                    asm volatile("global_load_dwordx4 %0, %1, off sc0 sc1"\
                                 : "=v"(ch[k]) : "v"(ap));               \
                }                                                        \
            asm volatile("s_waitcnt vmcnt(0)" ::: "memory");             \
            __builtin_amdgcn_sched_barrier(0);                           \
            _Pragma("unroll")                                            \
            for (int k = 0; k < 4; ++k)                                  \
                if ((need & (1<<k)) && __float_as_int(ch[k].w) == (tt))  \
                    need &= ~(1<<k);                                     \
            if (need) __builtin_amdgcn_s_sleep(1);                       \
        }                                                                \
        _Pragma("unroll")                                                \
        for (int k = 0; k < 4; ++k) {                                    \
            (hb0)[ldsoff[k]] = ch[k].x;                                  \
            if (!((onemask >> k) & 1)) {                                 \
                (hb0)[ldsoff[k] + HPITCH]   = ch[k].y;                   \
                (hb0)[ldsoff[k] + 2*HPITCH] = ch[k].z;                   \
            }                                                            \
        }                                                                \
    }

#define GRU_GATES(xr, xz, xn, ar, az, an)                                \
    {                                                                    \
        float rg = 1.f / (1.f + expf(-((xr) + (ar) + bhr)));             \
        float zg = 1.f / (1.f + expf(-((xz) + (az) + bhz)));             \
        float ng = tanhf((xn) + rg * ((an) + bhn));                      \
        hold = (1.f - zg) * ng + zg * hold;                              \
    }

#define PUBLISH(pbx, tt)                                                 \
    {                                                                    \
        int lb = lane & 32;                                              \
        float pa = __shfl(hold, lb + 0);                                 \
        float pbv = __shfl(hold, lb + 8);                                \
        float pc = __shfl(hold, lb + 16);                                \
        float pd = __shfl(hold, lb + 24);                                \
        if (c < 2) {                                                     \
            f32x4 val;                                                   \
            if (c == 0) { val.x = pa; val.y = pbv; val.z = pc; }         \
            else        { val.x = pd; val.y = 0.f; val.z = 0.f; }        \
            val.w = __int_as_float((tt) + 1);                            \
            f32x4* ap = (f32x4*)((pbx) + (size_t)(col*HCH + c)*16);      \
            asm volatile("global_store_dwordx4 %0, %1, off sc0 sc1"      \
                         :: "v"(ap), "v"(val) : "memory");               \
        }                                                                \
    }

    float hold = 0.f;

    // ---------------- prologue: t = 0 (h = 0 -> recurrent accums are 0)
    {
        float xr = xq[0], xz = xq[DIM], xn = xq[2*DIM];
        GRU_GATES(xr, xz, xn, 0.f, 0.f, 0.f);
    }
    PUBLISH(pb[0], 0);
    if ((c & 7) == 0)
        states[(size_t)(batch*SEQT + 0)*DIM + col] = hold;
    ISSUE_POLLS(pb[0]);
    // xp(1) prefetch
    float xr = xq[(size_t)D3], xz = xq[(size_t)D3 + DIM], xn = xq[(size_t)D3 + 2*DIM];

    // ---------------- main loop
    for (int t = 1; t < SEQT; ++t) {
        float* hb0 = &h_lds[t & 1][0][0];
        WAIT_FILL(pb[(t-1)&1], hb0, t);
        __syncthreads();

        // Phase B: partial dots, 4 batches x 3 gates, k-slice c
        float v[12];
        #pragma unroll
        for (int i = 0; i < 12; ++i) v[i] = 0.f;
        const float* hk = hb0 + c*4;
        #pragma unroll
        for (int bb = 0; bb < 4; ++bb) {
            const float* hr = hk + bb*HPITCH;
            #pragma unroll
            for (int m = 0; m < 6; ++m) {
                float4 h4 = *(const float4*)(hr + m*128);
                v[bb*3+0] += DOT4(h4, w4[0][m]);
                v[bb*3+1] += DOT4(h4, w4[1][m]);
                v[bb*3+2] += DOT4(h4, w4[2][m]);
            }
        }
        // reduce-scatter within 32 lanes: bits 4,3 -> batch; butterfly 4,2,1
        #pragma unroll
        for (int i = 0; i < 6; ++i) {
            float send = (c & 16) ? v[i] : v[i+6];
            float keep = (c & 16) ? v[i+6] : v[i];
            v[i] = keep + __shfl_xor(send, 16);
        }
        #pragma unroll
        for (int i = 0; i < 3; ++i) {
            float send = (c & 8) ? v[i] : v[i+3];
            float keep = (c & 8) ? v[i+3] : v[i];
            v[i] = keep + __shfl_xor(send, 8);
        }
        #pragma unroll
        for (int i = 0; i < 3; ++i) v[i] += __shfl_xor(v[i], 4);
        #pragma unroll
        for (int i = 0; i < 3; ++i) v[i] += __shfl_xor(v[i], 2);
        #pragma unroll
        for (int i = 0; i < 3; ++i) v[i] += __shfl_xor(v[i], 1);

        GRU_GATES(xr, xz, xn, v[0], v[1], v[2]);
        PUBLISH(pb[t&1], t);
        if ((c & 7) == 0)
            states[(size_t)(batch*SEQT + t)*DIM + col] = hold;

        if (t + 1 < SEQT) {
            ISSUE_POLLS(pb[t&1]);
            xr = xq[(size_t)(t+1)*D3];
            xz = xq[(size_t)(t+1)*D3 + DIM];
            xn = xq[(size_t)(t+1)*D3 + 2*DIM];
        }
    }
#undef ISSUE_POLLS
#undef WAIT_FILL
#undef GRU_GATES
#undef PUBLISH
}

// =========================================================
// K3: probs[r] = sigmoid(dot(states[r], w_act) + b_act)
// =========================================================
__global__ __launch_bounds__(256, 4) void k_probs(
    const float* __restrict__ states, const float* __restrict__ w_act,
    const float* __restrict__ b_act, float* __restrict__ probs,
    float* __restrict__ out_probs)
{
    int row  = blockIdx.x*4 + (threadIdx.x >> 6);
    int lane = threadIdx.x & 63;
    const float* sr = states + (size_t)row * DIM;
    float s = 0.f;
    #pragma unroll
    for (int i = 0; i < 3; ++i) {
        float4 v = *(const float4*)(sr + i*256 + lane*4);
        float4 w = *(const float4*)(w_act + i*256 + lane*4);
        s += v.x*w.x + v.y*w.y + v.z*w.z + v.w*w.w;
    }
    #pragma unroll
    for (int off = 32; off > 0; off >>= 1) s += __shfl_xor(s, off);
    if (lane == 0) {
        float pv = 1.f / (1.f + expf(-(s + b_act[0])));
        probs[row]     = pv;
        out_probs[row] = pv;
    }
}

// =========================================================
// K4: per-batch halting scan -> weights, segment bounds, n_segs
// =========================================================
__global__ void k_scan(const float* __restrict__ probs, float* __restrict__ weights,
                       int* __restrict__ seg_start, int* __restrict__ seg_end,
                       int* __restrict__ n_segs)
{
    int b = threadIdx.x;
    if (b >= BATCH) return;
    float acc = 0.f;
    int s = 0, start = 0;
    for (int t0 = 0; t0 < SEQT; t0 += 4) {
        float4 p4 = *(const float4*)(probs + b*SEQT + t0);
        float pv[4] = {p4.x, p4.y, p4.z, p4.w};
        #pragma unroll
        for (int k = 0; k < 4; ++k) {
            int t = t0 + k;
            float pp = pv[k];
            acc += pp;
            float w = pp;
            if (acc > VTHRESH) {
                w = pp - (acc - 1.0f);
                seg_start[b*SEQT + s] = start;
                seg_end[b*SEQT + s]   = t;
                s++; start = t + 1; acc = 0.f;
            }
            weights[b*SEQT + t] = w;
        }
    }
    n_segs[b] = s;
}

// =========================================================
// K5: embs row (b,s) = sum_{t in segment s} weights[b,t]*states[b,t,:]
// =========================================================
__global__ __launch_bounds__(256, 4) void k_embs(
    const float* __restrict__ states, const float* __restrict__ weights,
    const int* __restrict__ seg_start, const int* __restrict__ seg_end,
    const int* __restrict__ n_segs, float* __restrict__ out)
{
    int r = blockIdx.x;
    int b = r / SEQT;
    int s = r - b*SEQT;
    int tid = threadIdx.x;
    float a0 = 0.f, a1 = 0.f, a2 = 0.f;
    if (s < n_segs[b]) {
        int st = seg_start[r], en = seg_end[r];
        for (int t = st; t <= en; ++t) {
            float w = weights[b*SEQT + t];
            const float* sp = states + (size_t)(b*SEQT + t) * DIM;
            a0 += w * sp[tid];
            a1 += w * sp[tid + 256];
            a2 += w * sp[tid + 512];
        }
    }
    float* o = out + (size_t)r * DIM;
    o[tid]       = a0;
    o[tid + 256] = a1;
    o[tid + 512] = a2;
}

__global__ void k_init(float* hb) {
    hb[blockIdx.x * 256 + threadIdx.x] = 0.f;   // 98304 floats = 384KB
}

extern "C" void kernel_launch(void* const* d_in, const int* in_sizes, int n_in,
                              void* d_out, int out_size, void* d_ws, size_t ws_size,
                              hipStream_t stream)
{
    const int*   sent  = (const int*)d_in[0];
    const float* emb   = (const float*)d_in[1];
    const float* w_ih  = (const float*)d_in[2];
    const float* w_hh  = (const float*)d_in[3];
    const float* b_ih  = (const float*)d_in[4];
    const float* b_hh  = (const float*)d_in[5];
    const float* w_act = (const float*)d_in[6];
    const float* b_act = (const float*)d_in[7];
    float* out = (float*)d_out;

    char* ws = (char*)d_ws;
    float* xp      = (float*)(ws + OFF_XP);
    float* states  = (float*)(ws + OFF_ST);
    float* probs   = (float*)(ws + OFF_PR);
    float* weights = (float*)(ws + OFF_WT);
    int*   sstart  = (int*)(ws + OFF_SS);
    int*   send    = (int*)(ws + OFF_SE);
    int*   nsegs   = (int*)(ws + OFF_NS);
    char*  hbuf    = (char*)(ws + OFF_HB);

    k_init<<<384, 256, 0, stream>>>((float*)hbuf);
    k_xp<<<dim3(96, 18), 256, 0, stream>>>(sent, emb, w_ih, b_ih, xp);
    k_gru<<<512, 384, 0, stream>>>(w_hh, b_hh, xp, states, hbuf);
    k_probs<<<NROWS/4, 256, 0, stream>>>(states, w_act, b_act, probs,
                                         out + (size_t)NROWS * DIM);
    k_scan<<<1, 64, 0, stream>>>(probs, weights, sstart, send, nsegs);
    k_embs<<<NROWS, 256, 0, stream>>>(states, weights, sstart, send, nsegs, out);
}

// Round 4
// 3420.983 us; speedup vs baseline: 1.0827x; 1.0827x over previous
//
#include <hip/hip_runtime.h>
#include <math.h>

#define BATCH 32
#define SEQT 384
#define DIM 768
#define D3 2304
#define NROWS (BATCH*SEQT)      // 12288
#define VTHRESH 0.95f

typedef float  f32x4 __attribute__((ext_vector_type(4)));

// ---------------- workspace layout (bytes) ----------------
#define OFF_XP   ((size_t)0)
#define SZ_XP    ((size_t)NROWS * D3 * 4)            // 113,246,208
#define OFF_ST   (OFF_XP + SZ_XP)
#define SZ_ST    ((size_t)NROWS * DIM * 4)           // 37,748,736
#define OFF_PR   (OFF_ST + SZ_ST)
#define SZ_PR    ((size_t)NROWS * 4)
#define OFF_WT   (OFF_PR + SZ_PR)
#define OFF_SS   (OFF_WT + SZ_PR)
#define OFF_SE   (OFF_SS + SZ_PR)
#define OFF_NS   (OFF_SE + SZ_PR)
#define OFF_HB   (OFF_NS + 256)
// hbuf data: 2 parity x 4 bg x 768 cols x 2 chunks x 16B = 196,608 B
// flags:     4 bg x 64 WGs x 4B = 1,024 B  (monotonic step counters)
#define NBG 4               // batch groups (8 batches each)
#define BPG 8               // batches per group
#define BGBYTES ((size_t)(DIM * 2 * 16))     // 24,576 (2 chunks/col)
#define FLAGS_OFF ((size_t)2 * NBG * BGBYTES)        // 196,608
#define SZ_HB   (FLAGS_OFF + 1024)                   // 197,632
#define INIT_FLOATS 49408                            // SZ_HB/4

#define DOT4(a,b) ((a).x*(b).x + (a).y*(b).y + (a).z*(b).z + (a).w*(b).w)

// =========================================================
// K1: xp[m][n] = sum_k emb[sent[m]][k] * w_ih[n][k] + b_ih[n]
// =========================================================
__global__ __launch_bounds__(256, 2) void k_xp(
    const int* __restrict__ sent, const float* __restrict__ emb,
    const float* __restrict__ w_ih, const float* __restrict__ b_ih,
    float* __restrict__ xp)
{
    __shared__ float As[16][132];
    __shared__ float Bs[16][132];
    const int tid = threadIdx.x;
    const int mt = blockIdx.x, nt = blockIdx.y;
    const int tx = tid & 15, ty = tid >> 4;
    const int lm = tid >> 2;          // 0..63
    const int lk = (tid & 3) << 2;    // 0,4,8,12

    const long arow0 = (long)sent[mt*128 + lm] * DIM;
    const long arow1 = (long)sent[mt*128 + lm + 64] * DIM;
    const float* b0p = w_ih + (size_t)(nt*128 + lm) * DIM;
    const float* b1p = w_ih + (size_t)(nt*128 + lm + 64) * DIM;

    float acc[8][8];
    #pragma unroll
    for (int i = 0; i < 8; ++i)
        #pragma unroll
        for (int j = 0; j < 8; ++j) acc[i][j] = 0.f;

    for (int k0 = 0; k0 < DIM; k0 += 16) {
        float4 a0 = *(const float4*)(emb + arow0 + k0 + lk);
        float4 a1 = *(const float4*)(emb + arow1 + k0 + lk);
        float4 b0 = *(const float4*)(b0p + k0 + lk);
        float4 b1 = *(const float4*)(b1p + k0 + lk);
        __syncthreads();
        As[lk+0][lm] = a0.x; As[lk+1][lm] = a0.y; As[lk+2][lm] = a0.z; As[lk+3][lm] = a0.w;
        As[lk+0][lm+64] = a1.x; As[lk+1][lm+64] = a1.y; As[lk+2][lm+64] = a1.z; As[lk+3][lm+64] = a1.w;
        Bs[lk+0][lm] = b0.x; Bs[lk+1][lm] = b0.y; Bs[lk+2][lm] = b0.z; Bs[lk+3][lm] = b0.w;
        Bs[lk+0][lm+64] = b1.x; Bs[lk+1][lm+64] = b1.y; Bs[lk+2][lm+64] = b1.z; Bs[lk+3][lm+64] = b1.w;
        __syncthreads();
        #pragma unroll
        for (int k = 0; k < 16; ++k) {
            float4 av0 = *(const float4*)&As[k][ty*8];
            float4 av1 = *(const float4*)&As[k][ty*8+4];
            float4 bv0 = *(const float4*)&Bs[k][tx*8];
            float4 bv1 = *(const float4*)&Bs[k][tx*8+4];
            float a[8] = {av0.x,av0.y,av0.z,av0.w,av1.x,av1.y,av1.z,av1.w};
            float b[8] = {bv0.x,bv0.y,bv0.z,bv0.w,bv1.x,bv1.y,bv1.z,bv1.w};
            #pragma unroll
            for (int i = 0; i < 8; ++i)
                #pragma unroll
                for (int j = 0; j < 8; ++j)
                    acc[i][j] += a[i]*b[j];
        }
    }

    const int m0 = mt*128 + ty*8;
    const int n0 = nt*128 + tx*8;
    float4 bi0 = *(const float4*)(b_ih + n0);
    float4 bi1 = *(const float4*)(b_ih + n0 + 4);
    #pragma unroll
    for (int i = 0; i < 8; ++i) {
        float4 v0, v1;
        v0.x = acc[i][0] + bi0.x; v0.y = acc[i][1] + bi0.y;
        v0.z = acc[i][2] + bi0.z; v0.w = acc[i][3] + bi0.w;
        v1.x = acc[i][4] + bi1.x; v1.y = acc[i][5] + bi1.y;
        v1.z = acc[i][6] + bi1.z; v1.w = acc[i][7] + bi1.w;
        *(float4*)(xp + (size_t)(m0+i)*D3 + n0)     = v0;
        *(float4*)(xp + (size_t)(m0+i)*D3 + n0 + 4) = v1;
    }
}

// =========================================================
// K2: persistent GRU recurrence, v8 — flag-gated single-pass exchange.
//   R3 post-mortem: occupancy cannot be raised (HW runs 1 WG/CU; the
//   512-WG grid serialized in halves). R1-R3 invariant: VALUBusy*dur =
//   1.13 ms constant; v5's extra ~3 us/step = re-sweeps of the 24 KB
//   tagged buffer. v8 (on v5's 4bg x 64WG topology):
//   - producer: publish tagless chunks (sc1) -> per-wave vmcnt(0) ->
//     barrier -> tid0 stores monotonic flag = t+1 (sc1). Store-acks
//     before the barrier make all data visible before the flag.
//   - consumer: poll 64 flag dwords (256 B/sweep, one/lane, ballot),
//     then read the 24 KB of h exactly ONCE. Re-polls are ~100x
//     cheaper; data loads are gated so no tags needed (chunks 3->2
//     per col, 8 h values in 2x16B).
//   - monotonic flags: no parity reset; k_init zeroes per launch.
//     Back-pressure: flag>=t+1 requires every WG past fill(t), so
//     parity-(t-1) buffers are dead before overwrite (2-deep safe).
//   - xp(t+1) issued before the gated data loads: one vmcnt(0) drains
//     both; publish-side vmcnt(0) only waits on 16B stores.
// =========================================================
#define HPITCH 772

__global__ __launch_bounds__(384, 1) void k_gru(
    const float* __restrict__ w_hh, const float* __restrict__ b_hh,
    const float* __restrict__ xp, float* __restrict__ states,
    char* __restrict__ hbuf)
{
    __shared__ float h_lds[2][BPG][HPITCH];   // 49,408 B

    const int tid = threadIdx.x;
    const int jb  = blockIdx.x & 63;      // WG within bg
    const int bg  = blockIdx.x >> 6;      // 0..3
    const int j    = tid >> 6;            // wave 0..5
    const int lane = tid & 63;
    const int c    = lane & 31;
    const int bh   = lane >> 5;           // which of the wave's 2 cols
    const int col  = jb*12 + j*2 + bh;
    const int bloc = (c >> 2) & 7;        // batch-in-group
    const int batch = bg*BPG + bloc;

    // weights: gate g, k-slice {c*4 + m*128}
    float4 w4[3][6];
    #pragma unroll
    for (int g3 = 0; g3 < 3; ++g3) {
        const float* wr = w_hh + (size_t)(g3*DIM + col)*DIM + c*4;
        #pragma unroll
        for (int m = 0; m < 6; ++m)
            w4[g3][m] = *(const float4*)(wr + m*128);
    }
    const float bhr = b_hh[col];
    const float bhz = b_hh[DIM + col];
    const float bhn = b_hh[2*DIM + col];

    char* pb[2];
    pb[0] = hbuf + (size_t)(0*NBG + bg)*BGBYTES;
    pb[1] = hbuf + (size_t)(1*NBG + bg)*BGBYTES;
    int* flags = (int*)(hbuf + FLAGS_OFF) + bg*64;
    const int* fpoll = flags + lane;

    // consumer data assignment: 2 cols per thread
    const int cq0 = tid, cq1 = tid + 384;

    const float* xq = xp + (size_t)batch*SEQT*D3 + col;

#define GRU_GATES(xr, xz, xn, ar, az, an)                                \
    {                                                                    \
        float rg = 1.f / (1.f + expf(-((xr) + (ar) + bhr)));             \
        float zg = 1.f / (1.f + expf(-((xz) + (az) + bhz)));             \
        float ng = tanhf((xn) + rg * ((an) + bhn));                      \
        hold = (1.f - zg) * ng + zg * hold;                              \
    }

#define PUBLISH(pbx, tt)                                                 \
    {                                                                    \
        int lb = lane & 32;                                              \
        int sb = c & 16;                                                 \
        float q0 = __shfl(hold, lb + sb + 0);                            \
        float q1 = __shfl(hold, lb + sb + 4);                            \
        float q2 = __shfl(hold, lb + sb + 8);                            \
        float q3 = __shfl(hold, lb + sb + 12);                           \
        if ((c & 15) == 0) {                                             \
            f32x4 val; val.x = q0; val.y = q1; val.z = q2; val.w = q3;   \
            f32x4* ap = (f32x4*)((pbx) + (size_t)(col*2 + (c>>4))*16);   \
            asm volatile("global_store_dwordx4 %0, %1, off sc0 sc1"      \
                         :: "v"(ap), "v"(val) : "memory");               \
        }                                                                \
        if ((c & 3) == 0)                                                \
            states[(size_t)(batch*SEQT + (tt))*DIM + col] = hold;        \
        asm volatile("s_waitcnt vmcnt(0)" ::: "memory");                 \
        __syncthreads();                                                 \
        if (tid == 0) {                                                  \
            int tv = (tt) + 1;                                           \
            int* fp2 = flags + jb;                                       \
            asm volatile("global_store_dword %0, %1, off sc0 sc1"        \
                         :: "v"(fp2), "v"(tv) : "memory");               \
        }                                                                \
    }

    float hold = 0.f;

    // ---------------- prologue: t = 0 (h = 0 -> recurrent accums 0)
    float xr = xq[0], xz = xq[DIM], xn = xq[2*DIM];
    GRU_GATES(xr, xz, xn, 0.f, 0.f, 0.f);
    PUBLISH(pb[0], 0);
    // xp(1) prefetch
    float xrn = xq[(size_t)D3], xzn = xq[(size_t)D3 + DIM],
          xnn = xq[(size_t)D3 + 2*DIM];

    // ---------------- main loop
    for (int t = 1; t < SEQT; ++t) {
        // ---- flag gate: all 64 producers of this bg at step >= t
        {
            int fv;
            while (true) {
                asm volatile("global_load_dword %0, %1, off sc0 sc1"
                             : "=v"(fv) : "v"(fpoll));
                asm volatile("s_waitcnt vmcnt(0)" ::: "memory");
                __builtin_amdgcn_sched_barrier(0);
                if (__ballot(fv >= t) == ~0ull) break;
                __builtin_amdgcn_s_sleep(1);
            }
        }
        // consume xp(t) regs, then issue xp(t+1) prefetch
        xr = xrn; xz = xzn; xn = xnn;
        if (t + 1 < SEQT) {
            xrn = xq[(size_t)(t+1)*D3];
            xzn = xq[(size_t)(t+1)*D3 + DIM];
            xnn = xq[(size_t)(t+1)*D3 + 2*DIM];
        }
        // ---- single-pass gated data read (24 KB / WG)
        {
            const char* pbx = pb[(t-1)&1];
            f32x4 c0a, c0b, c1a, c1b;
            const f32x4* a0 = (const f32x4*)(pbx + (size_t)cq0*32);
            const f32x4* a1 = (const f32x4*)(pbx + (size_t)cq0*32 + 16);
            const f32x4* a2 = (const f32x4*)(pbx + (size_t)cq1*32);
            const f32x4* a3 = (const f32x4*)(pbx + (size_t)cq1*32 + 16);
            asm volatile("global_load_dwordx4 %0, %1, off sc0 sc1" : "=v"(c0a) : "v"(a0));
            asm volatile("global_load_dwordx4 %0, %1, off sc0 sc1" : "=v"(c0b) : "v"(a1));
            asm volatile("global_load_dwordx4 %0, %1, off sc0 sc1" : "=v"(c1a) : "v"(a2));
            asm volatile("global_load_dwordx4 %0, %1, off sc0 sc1" : "=v"(c1b) : "v"(a3));
            asm volatile("s_waitcnt vmcnt(0)" ::: "memory");
            __builtin_amdgcn_sched_barrier(0);
            float* hb0 = &h_lds[t & 1][0][0];
            hb0[0*HPITCH + cq0] = c0a.x; hb0[1*HPITCH + cq0] = c0a.y;
            hb0[2*HPITCH + cq0] = c0a.z; hb0[3*HPITCH + cq0] = c0a.w;
            hb0[4*HPITCH + cq0] = c0b.x; hb0[5*HPITCH + cq0] = c0b.y;
            hb0[6*HPITCH + cq0] = c0b.z; hb0[7*HPITCH + cq0] = c0b.w;
            hb0[0*HPITCH + cq1] = c1a.x; hb0[1*HPITCH + cq1] = c1a.y;
            hb0[2*HPITCH + cq1] = c1a.z; hb0[3*HPITCH + cq1] = c1a.w;
            hb0[4*HPITCH + cq1] = c1b.x; hb0[5*HPITCH + cq1] = c1b.y;
            hb0[6*HPITCH + cq1] = c1b.z; hb0[7*HPITCH + cq1] = c1b.w;
        }
        __syncthreads();

        // ---- Phase B: partial dots, 8 batches x 3 gates, k-slice c
        const float* hb0 = &h_lds[t & 1][0][0];
        float v[24];
        #pragma unroll
        for (int i = 0; i < 24; ++i) v[i] = 0.f;
        const float* hk = hb0 + c*4;
        #pragma unroll
        for (int bb = 0; bb < 8; ++bb) {
            const float* hr = hk + bb*HPITCH;
            #pragma unroll
            for (int m = 0; m < 6; ++m) {
                float4 h4 = *(const float4*)(hr + m*128);
                v[bb*3+0] += DOT4(h4, w4[0][m]);
                v[bb*3+1] += DOT4(h4, w4[1][m]);
                v[bb*3+2] += DOT4(h4, w4[2][m]);
            }
        }
        // ---- reduce-scatter (bits 4,3,2 -> batch), butterfly 2,1
        #pragma unroll
        for (int i = 0; i < 12; ++i) {
            float send = (c & 16) ? v[i] : v[i+12];
            float keep = (c & 16) ? v[i+12] : v[i];
            v[i] = keep + __shfl_xor(send, 16);
        }
        #pragma unroll
        for (int i = 0; i < 6; ++i) {
            float send = (c & 8) ? v[i] : v[i+6];
            float keep = (c & 8) ? v[i+6] : v[i];
            v[i] = keep + __shfl_xor(send, 8);
        }
        #pragma unroll
        for (int i = 0; i < 3; ++i) {
            float send = (c & 4) ? v[i] : v[i+3];
            float keep = (c & 4) ? v[i+3] : v[i];
            v[i] = keep + __shfl_xor(send, 4);
        }
        #pragma unroll
        for (int i = 0; i < 3; ++i) v[i] += __shfl_xor(v[i], 2);
        #pragma unroll
        for (int i = 0; i < 3; ++i) v[i] += __shfl_xor(v[i], 1);

        GRU_GATES(xr, xz, xn, v[0], v[1], v[2]);
        PUBLISH(pb[t&1], t);
    }
#undef GRU_GATES
#undef PUBLISH
}

// =========================================================
// K3: probs[r] = sigmoid(dot(states[r], w_act) + b_act)
// =========================================================
__global__ __launch_bounds__(256, 4) void k_probs(
    const float* __restrict__ states, const float* __restrict__ w_act,
    const float* __restrict__ b_act, float* __restrict__ probs,
    float* __restrict__ out_probs)
{
    int row  = blockIdx.x*4 + (threadIdx.x >> 6);
    int lane = threadIdx.x & 63;
    const float* sr = states + (size_t)row * DIM;
    float s = 0.f;
    #pragma unroll
    for (int i = 0; i < 3; ++i) {
        float4 v = *(const float4*)(sr + i*256 + lane*4);
        float4 w = *(const float4*)(w_act + i*256 + lane*4);
        s += v.x*w.x + v.y*w.y + v.z*w.z + v.w*w.w;
    }
    #pragma unroll
    for (int off = 32; off > 0; off >>= 1) s += __shfl_xor(s, off);
    if (lane == 0) {
        float pv = 1.f / (1.f + expf(-(s + b_act[0])));
        probs[row]     = pv;
        out_probs[row] = pv;
    }
}

// =========================================================
// K4: per-batch halting scan -> weights, segment bounds, n_segs
// =========================================================
__global__ void k_scan(const float* __restrict__ probs, float* __restrict__ weights,
                       int* __restrict__ seg_start, int* __restrict__ seg_end,
                       int* __restrict__ n_segs)
{
    int b = threadIdx.x;
    if (b >= BATCH) return;
    float acc = 0.f;
    int s = 0, start = 0;
    for (int t0 = 0; t0 < SEQT; t0 += 4) {
        float4 p4 = *(const float4*)(probs + b*SEQT + t0);
        float pv[4] = {p4.x, p4.y, p4.z, p4.w};
        #pragma unroll
        for (int k = 0; k < 4; ++k) {
            int t = t0 + k;
            float pp = pv[k];
            acc += pp;
            float w = pp;
            if (acc > VTHRESH) {
                w = pp - (acc - 1.0f);
                seg_start[b*SEQT + s] = start;
                seg_end[b*SEQT + s]   = t;
                s++; start = t + 1; acc = 0.f;
            }
            weights[b*SEQT + t] = w;
        }
    }
    n_segs[b] = s;
}

// =========================================================
// K5: embs row (b,s) = sum_{t in segment s} weights[b,t]*states[b,t,:]
// =========================================================
__global__ __launch_bounds__(256, 4) void k_embs(
    const float* __restrict__ states, const float* __restrict__ weights,
    const int* __restrict__ seg_start, const int* __restrict__ seg_end,
    const int* __restrict__ n_segs, float* __restrict__ out)
{
    int r = blockIdx.x;
    int b = r / SEQT;
    int s = r - b*SEQT;
    int tid = threadIdx.x;
    float a0 = 0.f, a1 = 0.f, a2 = 0.f;
    if (s < n_segs[b]) {
        int st = seg_start[r], en = seg_end[r];
        for (int t = st; t <= en; ++t) {
            float w = weights[b*SEQT + t];
            const float* sp = states + (size_t)(b*SEQT + t) * DIM;
            a0 += w * sp[tid];
            a1 += w * sp[tid + 256];
            a2 += w * sp[tid + 512];
        }
    }
    float* o = out + (size_t)r * DIM;
    o[tid]       = a0;
    o[tid + 256] = a1;
    o[tid + 512] = a2;
}

__global__ void k_init(float* hb) {
    int i = blockIdx.x * 256 + threadIdx.x;
    if (i < INIT_FLOATS) hb[i] = 0.f;     // data + flags
}

extern "C" void kernel_launch(void* const* d_in, const int* in_sizes, int n_in,
                              void* d_out, int out_size, void* d_ws, size_t ws_size,
                              hipStream_t stream)
{
    const int*   sent  = (const int*)d_in[0];
    const float* emb   = (const float*)d_in[1];
    const float* w_ih  = (const float*)d_in[2];
    const float* w_hh  = (const float*)d_in[3];
    const float* b_ih  = (const float*)d_in[4];
    const float* b_hh  = (const float*)d_in[5];
    const float* w_act = (const float*)d_in[6];
    const float* b_act = (const float*)d_in[7];
    float* out = (float*)d_out;

    char* ws = (char*)d_ws;
    float* xp      = (float*)(ws + OFF_XP);
    float* states  = (float*)(ws + OFF_ST);
    float* probs   = (float*)(ws + OFF_PR);
    float* weights = (float*)(ws + OFF_WT);
    int*   sstart  = (int*)(ws + OFF_SS);
    int*   send    = (int*)(ws + OFF_SE);
    int*   nsegs   = (int*)(ws + OFF_NS);
    char*  hbuf    = (char*)(ws + OFF_HB);

    k_init<<<194, 256, 0, stream>>>((float*)hbuf);
    k_xp<<<dim3(96, 18), 256, 0, stream>>>(sent, emb, w_ih, b_ih, xp);
    k_gru<<<256, 384, 0, stream>>>(w_hh, b_hh, xp, states, hbuf);
    k_probs<<<NROWS/4, 256, 0, stream>>>(states, w_act, b_act, probs,
                                         out + (size_t)NROWS * DIM);
    k_scan<<<1, 64, 0, stream>>>(probs, weights, sstart, send, nsegs);
    k_embs<<<NROWS, 256, 0, stream>>>(states, weights, sstart, send, nsegs, out);
}

// Round 5
// 2383.142 us; speedup vs baseline: 1.5543x; 1.4355x over previous
//
#include <hip/hip_runtime.h>
#include <math.h>

#define BATCH 32
#define SEQT 384
#define DIM 768
#define D3 2304
#define NROWS (BATCH*SEQT)      // 12288
#define VTHRESH 0.95f

typedef float  f32x4 __attribute__((ext_vector_type(4)));

// ---------------- workspace layout (bytes) ----------------
#define OFF_XP   ((size_t)0)
#define SZ_XP    ((size_t)NROWS * D3 * 4)            // 113,246,208
#define OFF_ST   (OFF_XP + SZ_XP)
#define SZ_ST    ((size_t)NROWS * DIM * 4)           // 37,748,736
#define OFF_PR   (OFF_ST + SZ_ST)
#define SZ_PR    ((size_t)NROWS * 4)
#define OFF_WT   (OFF_PR + SZ_PR)
#define OFF_SS   (OFF_WT + SZ_PR)
#define OFF_SE   (OFF_SS + SZ_PR)
#define OFF_NS   (OFF_SE + SZ_PR)
#define OFF_HB   (OFF_NS + 256)
// hbuf: 2 parity x 8 bg x 768 cols x 2 chunks x 16B = 393,216 B
// chunk layout per col: s0=[b0,b1,b2,tag]  s1=[b3,-,-,tag]
#define NBG 8               // batch groups (4 batches each)
#define BPG 4               // batches per group
#define WPB 32              // WGs per bg
#define CPW 24              // cols per WG
#define BGBYTES ((size_t)(DIM * 2 * 16))     // 24,576
#define SZ_HB   ((size_t)2 * NBG * BGBYTES)  // 393,216
#define INIT_FLOATS (SZ_HB/4)                // 98,304

#define DOT4(a,b) ((a).x*(b).x + (a).y*(b).y + (a).z*(b).z + (a).w*(b).w)

// =========================================================
// K1: xp[m][n] = sum_k emb[sent[m]][k] * w_ih[n][k] + b_ih[n]
// =========================================================
__global__ __launch_bounds__(256, 2) void k_xp(
    const int* __restrict__ sent, const float* __restrict__ emb,
    const float* __restrict__ w_ih, const float* __restrict__ b_ih,
    float* __restrict__ xp)
{
    __shared__ float As[16][132];
    __shared__ float Bs[16][132];
    const int tid = threadIdx.x;
    const int mt = blockIdx.x, nt = blockIdx.y;
    const int tx = tid & 15, ty = tid >> 4;
    const int lm = tid >> 2;          // 0..63
    const int lk = (tid & 3) << 2;    // 0,4,8,12

    const long arow0 = (long)sent[mt*128 + lm] * DIM;
    const long arow1 = (long)sent[mt*128 + lm + 64] * DIM;
    const float* b0p = w_ih + (size_t)(nt*128 + lm) * DIM;
    const float* b1p = w_ih + (size_t)(nt*128 + lm + 64) * DIM;

    float acc[8][8];
    #pragma unroll
    for (int i = 0; i < 8; ++i)
        #pragma unroll
        for (int j = 0; j < 8; ++j) acc[i][j] = 0.f;

    for (int k0 = 0; k0 < DIM; k0 += 16) {
        float4 a0 = *(const float4*)(emb + arow0 + k0 + lk);
        float4 a1 = *(const float4*)(emb + arow1 + k0 + lk);
        float4 b0 = *(const float4*)(b0p + k0 + lk);
        float4 b1 = *(const float4*)(b1p + k0 + lk);
        __syncthreads();
        As[lk+0][lm] = a0.x; As[lk+1][lm] = a0.y; As[lk+2][lm] = a0.z; As[lk+3][lm] = a0.w;
        As[lk+0][lm+64] = a1.x; As[lk+1][lm+64] = a1.y; As[lk+2][lm+64] = a1.z; As[lk+3][lm+64] = a1.w;
        Bs[lk+0][lm] = b0.x; Bs[lk+1][lm] = b0.y; Bs[lk+2][lm] = b0.z; Bs[lk+3][lm] = b0.w;
        Bs[lk+0][lm+64] = b1.x; Bs[lk+1][lm+64] = b1.y; Bs[lk+2][lm+64] = b1.z; Bs[lk+3][lm+64] = b1.w;
        __syncthreads();
        #pragma unroll
        for (int k = 0; k < 16; ++k) {
            float4 av0 = *(const float4*)&As[k][ty*8];
            float4 av1 = *(const float4*)&As[k][ty*8+4];
            float4 bv0 = *(const float4*)&Bs[k][tx*8];
            float4 bv1 = *(const float4*)&Bs[k][tx*8+4];
            float a[8] = {av0.x,av0.y,av0.z,av0.w,av1.x,av1.y,av1.z,av1.w};
            float b[8] = {bv0.x,bv0.y,bv0.z,bv0.w,bv1.x,bv1.y,bv1.z,bv1.w};
            #pragma unroll
            for (int i = 0; i < 8; ++i)
                #pragma unroll
                for (int j = 0; j < 8; ++j)
                    acc[i][j] += a[i]*b[j];
        }
    }

    const int m0 = mt*128 + ty*8;
    const int n0 = nt*128 + tx*8;
    float4 bi0 = *(const float4*)(b_ih + n0);
    float4 bi1 = *(const float4*)(b_ih + n0 + 4);
    #pragma unroll
    for (int i = 0; i < 8; ++i) {
        float4 v0, v1;
        v0.x = acc[i][0] + bi0.x; v0.y = acc[i][1] + bi0.y;
        v0.z = acc[i][2] + bi0.z; v0.w = acc[i][3] + bi0.w;
        v1.x = acc[i][4] + bi1.x; v1.y = acc[i][5] + bi1.y;
        v1.z = acc[i][6] + bi1.z; v1.w = acc[i][7] + bi1.w;
        *(float4*)(xp + (size_t)(m0+i)*D3 + n0)     = v0;
        *(float4*)(xp + (size_t)(m0+i)*D3 + n0 + 4) = v1;
    }
}

// =========================================================
// K2: persistent GRU recurrence, v9 — v5 protocol, fan-in 32.
//   R4 post-mortem: the flag scheme (v8) added a serial 2nd RT and
//   coupled publish to the slowest wave (vmcnt0+barrier before flag)
//   -> worse than v5's 1-RT tagged chunks. v9 reverts to v5's exact
//   protocol (per-wave immediate tagged 16B publish, speculative
//   sweep issued at step end, resweep only missing chunks, 1 barrier
//   per step) and halves the straggler set:
//   - 8 bg x 4 batches x 32 WGs: consumer waits on max-of-32
//     producers (was 64); sweep volume 24 KB (4 chunks/thread, was 6).
//   - per-thread compute UNCHANGED (24 cols x 4 batches = 576 FMA).
//   - wave = 4 col-groups of 16 lanes; k-slice c16*4+m*64; reduce
//     inside 16 lanes only (xor8/4 scatter -> batch=c16>>2, xor2/1).
//   - LDS dot reads are 4-way same-address broadcast (conflict-free).
//   - weights 144 VGPR/thread: fine at the pinned 1 WG/CU.
//   2-deep parity safety proof unchanged (per-wave: publish(t) =>
//   swept all of t-1 => every wave published t-1 => every wave's
//   sweep of (t-2)-parity completed before this overwrite).
// =========================================================
#define HPITCH 772

__global__ __launch_bounds__(384, 1) void k_gru(
    const float* __restrict__ w_hh, const float* __restrict__ b_hh,
    const float* __restrict__ xp, float* __restrict__ states,
    char* __restrict__ hbuf)
{
    __shared__ float h_lds[2][BPG][HPITCH];   // 24,704 B

    const int tid = threadIdx.x;
    const int jb  = blockIdx.x & 31;      // WG within bg
    const int bg  = blockIdx.x >> 5;      // 0..7
    const int w    = tid >> 6;            // wave 0..5
    const int lane = tid & 63;
    const int g    = lane >> 4;           // col-group 0..3
    const int c16  = lane & 15;
    const int col  = jb*CPW + w*4 + g;
    const int bloc = c16 >> 2;            // batch-in-group 0..3
    const int batch = bg*BPG + bloc;

    // weights: gate g3, this lane's col, k-slice {c16*4 + m*64}
    float4 w4[3][12];
    #pragma unroll
    for (int g3 = 0; g3 < 3; ++g3) {
        const float* wr = w_hh + (size_t)(g3*DIM + col)*DIM + c16*4;
        #pragma unroll
        for (int m = 0; m < 12; ++m)
            w4[g3][m] = *(const float4*)(wr + m*64);
    }
    const float bhr = b_hh[col];
    const float bhz = b_hh[DIM + col];
    const float bhn = b_hh[2*DIM + col];

    // consumer chunk assignment: q = i*384 + tid; col_q = q>>1, s_q = q&1
    int goff[4], ldsoff[4], onemask = 0;
    #pragma unroll
    for (int i = 0; i < 4; ++i) {
        int q = i*384 + tid;
        int cq = q >> 1, sq = q & 1;
        goff[i]   = q << 4;
        ldsoff[i] = (sq ? 3 : 0)*HPITCH + cq;
        if (sq) onemask |= (1<<i);      // s=1 carries only batch 3
    }

    char* pb[2];
    pb[0] = hbuf + (size_t)(0*NBG + bg)*BGBYTES;
    pb[1] = hbuf + (size_t)(1*NBG + bg)*BGBYTES;

    const float* xq = xp + (size_t)batch*SEQT*D3 + col;

    f32x4 ch[4];

#define ISSUE_POLLS(pbx)                                                 \
    {                                                                    \
        _Pragma("unroll")                                                \
        for (int k = 0; k < 4; ++k) {                                    \
            const f32x4* ap = (const f32x4*)((pbx) + goff[k]);           \
            asm volatile("global_load_dwordx4 %0, %1, off sc0 sc1"       \
                         : "=v"(ch[k]) : "v"(ap));                       \
        }                                                                \
    }

#define WAIT_FILL(pbx, hb0, tt)                                          \
    {                                                                    \
        asm volatile("s_waitcnt vmcnt(0)" ::: "memory");                 \
        __builtin_amdgcn_sched_barrier(0);                               \
        int need = 15;                                                   \
        _Pragma("unroll")                                                \
        for (int k = 0; k < 4; ++k)                                      \
            if (__float_as_int(ch[k].w) == (tt)) need &= ~(1<<k);        \
        while (need) {                                                   \
            _Pragma("unroll")                                            \
            for (int k = 0; k < 4; ++k)                                  \
                if (need & (1<<k)) {                                     \
                    const f32x4* ap = (const f32x4*)((pbx) + goff[k]);   \
                    asm volatile("global_load_dwordx4 %0, %1, off sc0 sc1"\
                                 : "=v"(ch[k]) : "v"(ap));               \
                }                                                        \
            asm volatile("s_waitcnt vmcnt(0)" ::: "memory");             \
            __builtin_amdgcn_sched_barrier(0);                           \
            _Pragma("unroll")                                            \
            for (int k = 0; k < 4; ++k)                                  \
                if ((need & (1<<k)) && __float_as_int(ch[k].w) == (tt))  \
                    need &= ~(1<<k);                                     \
            if (need) __builtin_amdgcn_s_sleep(1);                       \
        }                                                                \
        _Pragma("unroll")                                                \
        for (int k = 0; k < 4; ++k) {                                    \
            (hb0)[ldsoff[k]] = ch[k].x;                                  \
            if (!((onemask >> k) & 1)) {                                 \
                (hb0)[ldsoff[k] + HPITCH]   = ch[k].y;                   \
                (hb0)[ldsoff[k] + 2*HPITCH] = ch[k].z;                   \
            }                                                            \
        }                                                                \
    }

#define GRU_GATES(xr, xz, xn, ar, az, an)                                \
    {                                                                    \
        float rg = 1.f / (1.f + expf(-((xr) + (ar) + bhr)));             \
        float zg = 1.f / (1.f + expf(-((xz) + (az) + bhz)));             \
        float ng = tanhf((xn) + rg * ((an) + bhn));                      \
        hold = (1.f - zg) * ng + zg * hold;                              \
    }

    // publish: lanes 0..7 build chunks for this wave's 4 cols x 2 subs.
    // lane p: col-group gp=p>>1, sub sq=p&1.
    //   sq0 chunk = [h(b0),h(b1),h(b2),tag]  (sources gp*16+{0,4,8})
    //   sq1 chunk = [h(b3),  -,   -, tag]    (source  gp*16+12)
#define PUBLISH(pbx, tt)                                                 \
    {                                                                    \
        int gp = (lane >> 1) & 3;                                        \
        int sq = lane & 1;                                               \
        float q0 = __shfl(hold, gp*16 + (sq ? 12 : 0));                  \
        float q1 = __shfl(hold, gp*16 + 4);                              \
        float q2 = __shfl(hold, gp*16 + 8);                              \
        if (lane < 8) {                                                  \
            f32x4 val;                                                   \
            val.x = q0; val.y = q1; val.z = q2;                          \
            val.w = __int_as_float((tt) + 1);                            \
            int colp = jb*CPW + w*4 + gp;                                \
            f32x4* ap = (f32x4*)((pbx) + (size_t)(colp*2 + sq)*16);      \
            asm volatile("global_store_dwordx4 %0, %1, off sc0 sc1"      \
                         :: "v"(ap), "v"(val) : "memory");               \
        }                                                                \
        if ((c16 & 3) == 0)                                              \
            states[(size_t)(batch*SEQT + (tt))*DIM + col] = hold;        \
    }

    float hold = 0.f;

    // ---------------- prologue: t = 0 (h = 0 -> recurrent accums 0)
    float xr = xq[0], xz = xq[DIM], xn = xq[2*DIM];
    GRU_GATES(xr, xz, xn, 0.f, 0.f, 0.f);
    PUBLISH(pb[0], 0);
    ISSUE_POLLS(pb[0]);                  // speculative sweep for t=1
    // xp(1) prefetch
    float xrn = xq[(size_t)D3], xzn = xq[(size_t)D3 + DIM],
          xnn = xq[(size_t)D3 + 2*DIM];

    // ---------------- main loop
    for (int t = 1; t < SEQT; ++t) {
        float* hb0 = &h_lds[t & 1][0][0];
        WAIT_FILL(pb[(t-1)&1], hb0, t);
        // rotate xp regs; issue next prefetch (drained by t+1's sweep)
        xr = xrn; xz = xzn; xn = xnn;
        if (t + 1 < SEQT) {
            xrn = xq[(size_t)(t+1)*D3];
            xzn = xq[(size_t)(t+1)*D3 + DIM];
            xnn = xq[(size_t)(t+1)*D3 + 2*DIM];
        }
        __syncthreads();

        // ---- partial dots: 4 batches x 3 gates, k-slice c16*4+m*64
        float v[12];
        #pragma unroll
        for (int i = 0; i < 12; ++i) v[i] = 0.f;
        const float* hk = hb0 + c16*4;
        #pragma unroll
        for (int bb = 0; bb < 4; ++bb) {
            const float* hr = hk + bb*HPITCH;
            #pragma unroll
            for (int m = 0; m < 12; ++m) {
                float4 h4 = *(const float4*)(hr + m*64);
                v[bb*3+0] += DOT4(h4, w4[0][m]);
                v[bb*3+1] += DOT4(h4, w4[1][m]);
                v[bb*3+2] += DOT4(h4, w4[2][m]);
            }
        }
        // ---- reduce within 16-lane group: bits 3,2 -> batch; 1,0 butterfly
        #pragma unroll
        for (int i = 0; i < 6; ++i) {
            float send = (c16 & 8) ? v[i] : v[i+6];
            float keep = (c16 & 8) ? v[i+6] : v[i];
            v[i] = keep + __shfl_xor(send, 8);
        }
        #pragma unroll
        for (int i = 0; i < 3; ++i) {
            float send = (c16 & 4) ? v[i] : v[i+3];
            float keep = (c16 & 4) ? v[i+3] : v[i];
            v[i] = keep + __shfl_xor(send, 4);
        }
        #pragma unroll
        for (int i = 0; i < 3; ++i) v[i] += __shfl_xor(v[i], 2);
        #pragma unroll
        for (int i = 0; i < 3; ++i) v[i] += __shfl_xor(v[i], 1);

        GRU_GATES(xr, xz, xn, v[0], v[1], v[2]);
        PUBLISH(pb[t&1], t);
        if (t + 1 < SEQT)
            ISSUE_POLLS(pb[t&1]);        // speculative sweep for t+1
    }
#undef ISSUE_POLLS
#undef WAIT_FILL
#undef GRU_GATES
#undef PUBLISH
}

// =========================================================
// K3: probs[r] = sigmoid(dot(states[r], w_act) + b_act)
// =========================================================
__global__ __launch_bounds__(256, 4) void k_probs(
    const float* __restrict__ states, const float* __restrict__ w_act,
    const float* __restrict__ b_act, float* __restrict__ probs,
    float* __restrict__ out_probs)
{
    int row  = blockIdx.x*4 + (threadIdx.x >> 6);
    int lane = threadIdx.x & 63;
    const float* sr = states + (size_t)row * DIM;
    float s = 0.f;
    #pragma unroll
    for (int i = 0; i < 3; ++i) {
        float4 v = *(const float4*)(sr + i*256 + lane*4);
        float4 w = *(const float4*)(w_act + i*256 + lane*4);
        s += v.x*w.x + v.y*w.y + v.z*w.z + v.w*w.w;
    }
    #pragma unroll
    for (int off = 32; off > 0; off >>= 1) s += __shfl_xor(s, off);
    if (lane == 0) {
        float pv = 1.f / (1.f + expf(-(s + b_act[0])));
        probs[row]     = pv;
        out_probs[row] = pv;
    }
}

// =========================================================
// K4: per-batch halting scan -> weights, segment bounds, n_segs
// =========================================================
__global__ void k_scan(const float* __restrict__ probs, float* __restrict__ weights,
                       int* __restrict__ seg_start, int* __restrict__ seg_end,
                       int* __restrict__ n_segs)
{
    int b = threadIdx.x;
    if (b >= BATCH) return;
    float acc = 0.f;
    int s = 0, start = 0;
    for (int t0 = 0; t0 < SEQT; t0 += 4) {
        float4 p4 = *(const float4*)(probs + b*SEQT + t0);
        float pv[4] = {p4.x, p4.y, p4.z, p4.w};
        #pragma unroll
        for (int k = 0; k < 4; ++k) {
            int t = t0 + k;
            float pp = pv[k];
            acc += pp;
            float w = pp;
            if (acc > VTHRESH) {
                w = pp - (acc - 1.0f);
                seg_start[b*SEQT + s] = start;
                seg_end[b*SEQT + s]   = t;
                s++; start = t + 1; acc = 0.f;
            }
            weights[b*SEQT + t] = w;
        }
    }
    n_segs[b] = s;
}

// =========================================================
// K5: embs row (b,s) = sum_{t in segment s} weights[b,t]*states[b,t,:]
// =========================================================
__global__ __launch_bounds__(256, 4) void k_embs(
    const float* __restrict__ states, const float* __restrict__ weights,
    const int* __restrict__ seg_start, const int* __restrict__ seg_end,
    const int* __restrict__ n_segs, float* __restrict__ out)
{
    int r = blockIdx.x;
    int b = r / SEQT;
    int s = r - b*SEQT;
    int tid = threadIdx.x;
    float a0 = 0.f, a1 = 0.f, a2 = 0.f;
    if (s < n_segs[b]) {
        int st = seg_start[r], en = seg_end[r];
        for (int t = st; t <= en; ++t) {
            float w = weights[b*SEQT + t];
            const float* sp = states + (size_t)(b*SEQT + t) * DIM;
            a0 += w * sp[tid];
            a1 += w * sp[tid + 256];
            a2 += w * sp[tid + 512];
        }
    }
    float* o = out + (size_t)r * DIM;
    o[tid]       = a0;
    o[tid + 256] = a1;
    o[tid + 512] = a2;
}

__global__ void k_init(float* hb) {
    int i = blockIdx.x * 256 + threadIdx.x;
    if (i < INIT_FLOATS) hb[i] = 0.f;
}

extern "C" void kernel_launch(void* const* d_in, const int* in_sizes, int n_in,
                              void* d_out, int out_size, void* d_ws, size_t ws_size,
                              hipStream_t stream)
{
    const int*   sent  = (const int*)d_in[0];
    const float* emb   = (const float*)d_in[1];
    const float* w_ih  = (const float*)d_in[2];
    const float* w_hh  = (const float*)d_in[3];
    const float* b_ih  = (const float*)d_in[4];
    const float* b_hh  = (const float*)d_in[5];
    const float* w_act = (const float*)d_in[6];
    const float* b_act = (const float*)d_in[7];
    float* out = (float*)d_out;

    char* ws = (char*)d_ws;
    float* xp      = (float*)(ws + OFF_XP);
    float* states  = (float*)(ws + OFF_ST);
    float* probs   = (float*)(ws + OFF_PR);
    float* weights = (float*)(ws + OFF_WT);
    int*   sstart  = (int*)(ws + OFF_SS);
    int*   send    = (int*)(ws + OFF_SE);
    int*   nsegs   = (int*)(ws + OFF_NS);
    char*  hbuf    = (char*)(ws + OFF_HB);

    k_init<<<384, 256, 0, stream>>>((float*)hbuf);
    k_xp<<<dim3(96, 18), 256, 0, stream>>>(sent, emb, w_ih, b_ih, xp);
    k_gru<<<256, 384, 0, stream>>>(w_hh, b_hh, xp, states, hbuf);
    k_probs<<<NROWS/4, 256, 0, stream>>>(states, w_act, b_act, probs,
                                         out + (size_t)NROWS * DIM);
    k_scan<<<1, 64, 0, stream>>>(probs, weights, sstart, send, nsegs);
    k_embs<<<NROWS, 256, 0, stream>>>(states, weights, sstart, send, nsegs, out);
}

// Round 6
// 2333.504 us; speedup vs baseline: 1.5873x; 1.0213x over previous
//
#include <hip/hip_runtime.h>
#include <math.h>

#define BATCH 32
#define SEQT 384
#define DIM 768
#define D3 2304
#define NROWS (BATCH*SEQT)      // 12288
#define VTHRESH 0.95f

typedef float  f32x4 __attribute__((ext_vector_type(4)));

// ---------------- workspace layout (bytes) ----------------
#define OFF_XP   ((size_t)0)
#define SZ_XP    ((size_t)NROWS * D3 * 4)            // 113,246,208
#define OFF_ST   (OFF_XP + SZ_XP)
#define SZ_ST    ((size_t)NROWS * DIM * 4)           // 37,748,736
#define OFF_PR   (OFF_ST + SZ_ST)
#define SZ_PR    ((size_t)NROWS * 4)
#define OFF_WT   (OFF_PR + SZ_PR)
#define OFF_SS   (OFF_WT + SZ_PR)
#define OFF_SE   (OFF_SS + SZ_PR)
#define OFF_NS   (OFF_SE + SZ_PR)
#define OFF_HB   (OFF_NS + 256)
// hbuf: 2 parity x 8 bg x 768 cols x 2 chunks x 16B = 393,216 B
// chunk layout per col: s0=[b0,b1,b2,tag]  s1=[b3,-,-,tag]
#define NBG 8               // batch groups (4 batches each)
#define BPG 4               // batches per group
#define WPB 32              // WGs per bg
#define CPW 24              // cols per WG
#define BGBYTES ((size_t)(DIM * 2 * 16))     // 24,576
#define SZ_HB   ((size_t)2 * NBG * BGBYTES)  // 393,216
#define INIT_FLOATS (SZ_HB/4)                // 98,304

#define DOT4(a,b) ((a).x*(b).x + (a).y*(b).y + (a).z*(b).z + (a).w*(b).w)

// =========================================================
// K1: xp[m][n] = sum_k emb[sent[m]][k] * w_ih[n][k] + b_ih[n]
// =========================================================
__global__ __launch_bounds__(256, 2) void k_xp(
    const int* __restrict__ sent, const float* __restrict__ emb,
    const float* __restrict__ w_ih, const float* __restrict__ b_ih,
    float* __restrict__ xp)
{
    __shared__ float As[16][132];
    __shared__ float Bs[16][132];
    const int tid = threadIdx.x;
    const int mt = blockIdx.x, nt = blockIdx.y;
    const int tx = tid & 15, ty = tid >> 4;
    const int lm = tid >> 2;          // 0..63
    const int lk = (tid & 3) << 2;    // 0,4,8,12

    const long arow0 = (long)sent[mt*128 + lm] * DIM;
    const long arow1 = (long)sent[mt*128 + lm + 64] * DIM;
    const float* b0p = w_ih + (size_t)(nt*128 + lm) * DIM;
    const float* b1p = w_ih + (size_t)(nt*128 + lm + 64) * DIM;

    float acc[8][8];
    #pragma unroll
    for (int i = 0; i < 8; ++i)
        #pragma unroll
        for (int j = 0; j < 8; ++j) acc[i][j] = 0.f;

    for (int k0 = 0; k0 < DIM; k0 += 16) {
        float4 a0 = *(const float4*)(emb + arow0 + k0 + lk);
        float4 a1 = *(const float4*)(emb + arow1 + k0 + lk);
        float4 b0 = *(const float4*)(b0p + k0 + lk);
        float4 b1 = *(const float4*)(b1p + k0 + lk);
        __syncthreads();
        As[lk+0][lm] = a0.x; As[lk+1][lm] = a0.y; As[lk+2][lm] = a0.z; As[lk+3][lm] = a0.w;
        As[lk+0][lm+64] = a1.x; As[lk+1][lm+64] = a1.y; As[lk+2][lm+64] = a1.z; As[lk+3][lm+64] = a1.w;
        Bs[lk+0][lm] = b0.x; Bs[lk+1][lm] = b0.y; Bs[lk+2][lm] = b0.z; Bs[lk+3][lm] = b0.w;
        Bs[lk+0][lm+64] = b1.x; Bs[lk+1][lm+64] = b1.y; Bs[lk+2][lm+64] = b1.z; Bs[lk+3][lm+64] = b1.w;
        __syncthreads();
        #pragma unroll
        for (int k = 0; k < 16; ++k) {
            float4 av0 = *(const float4*)&As[k][ty*8];
            float4 av1 = *(const float4*)&As[k][ty*8+4];
            float4 bv0 = *(const float4*)&Bs[k][tx*8];
            float4 bv1 = *(const float4*)&Bs[k][tx*8+4];
            float a[8] = {av0.x,av0.y,av0.z,av0.w,av1.x,av1.y,av1.z,av1.w};
            float b[8] = {bv0.x,bv0.y,bv0.z,bv0.w,bv1.x,bv1.y,bv1.z,bv1.w};
            #pragma unroll
            for (int i = 0; i < 8; ++i)
                #pragma unroll
                for (int j = 0; j < 8; ++j)
                    acc[i][j] += a[i]*b[j];
        }
    }

    const int m0 = mt*128 + ty*8;
    const int n0 = nt*128 + tx*8;
    float4 bi0 = *(const float4*)(b_ih + n0);
    float4 bi1 = *(const float4*)(b_ih + n0 + 4);
    #pragma unroll
    for (int i = 0; i < 8; ++i) {
        float4 v0, v1;
        v0.x = acc[i][0] + bi0.x; v0.y = acc[i][1] + bi0.y;
        v0.z = acc[i][2] + bi0.z; v0.w = acc[i][3] + bi0.w;
        v1.x = acc[i][4] + bi1.x; v1.y = acc[i][5] + bi1.y;
        v1.z = acc[i][6] + bi1.z; v1.w = acc[i][7] + bi1.w;
        *(float4*)(xp + (size_t)(m0+i)*D3 + n0)     = v0;
        *(float4*)(xp + (size_t)(m0+i)*D3 + n0 + 4) = v1;
    }
}

// =========================================================
// K2: persistent GRU recurrence, v10 — wide WG (12 waves), v9 protocol.
//   R5 post-mortem: VGPR_Count 116 < 144-reg weight array => compiler
//   re-loads w_hh from L2 inside the t-loop; VALUBusy 53% with only
//   1.5 waves/SIMD to hide exchange-RT + dependency stalls.
//   v10: same 8bg x 32WG grid & tagged 1-RT protocol, but 768-thread
//   WGs (12 waves = 3 waves/SIMD):
//   - per-thread work halves (288 FMA, 2 poll chunks); per-SIMD issue
//     total unchanged; latency hiding doubles (m114 co-scheduling).
//   - 32 lanes per col -> w4 = 3x6 f32x4 = 72 VGPR: weights are
//     resident again (structural fix for the reload).
//   - reduce tree: xor16/xor8 scatter (batch=(c32>>3)&3), xor4/2/1
//     butterfly (v7's proven 32-lane version).
//   - publish: 4 chunks/wave from lanes 0..3 via 3 shfls.
//   2-deep parity safety proof unchanged (publish(t) => passed
//   WAIT(t-1) => all WGs published t-1 => nobody still in WAIT(t-2)).
// =========================================================
#define HPITCH 772

__global__ __launch_bounds__(768, 1) void k_gru(
    const float* __restrict__ w_hh, const float* __restrict__ b_hh,
    const float* __restrict__ xp, float* __restrict__ states,
    char* __restrict__ hbuf)
{
    __shared__ float h_lds[2][BPG][HPITCH];   // 24,704 B

    const int tid = threadIdx.x;
    const int jb  = blockIdx.x & 31;      // WG within bg
    const int bg  = blockIdx.x >> 5;      // 0..7
    const int w    = tid >> 6;            // wave 0..11
    const int lane = tid & 63;
    const int half = lane >> 5;           // which of the wave's 2 cols
    const int c32  = lane & 31;
    const int col  = jb*CPW + w*2 + half;
    const int bloc = (c32 >> 3) & 3;      // batch-in-group 0..3
    const int batch = bg*BPG + bloc;

    // weights: gate g3, this lane's col, k-slice {c32*4 + m*128}
    f32x4 w4[3][6];
    #pragma unroll
    for (int g3 = 0; g3 < 3; ++g3) {
        const float* wr = w_hh + (size_t)(g3*DIM + col)*DIM + c32*4;
        #pragma unroll
        for (int m = 0; m < 6; ++m)
            w4[g3][m] = *(const f32x4*)(wr + m*128);
    }
    const float bhr = b_hh[col];
    const float bhz = b_hh[DIM + col];
    const float bhn = b_hh[2*DIM + col];

    // consumer chunk assignment: q = i*768 + tid; col_q = q>>1, s_q = q&1
    int goff[2], ldsoff[2], onemask = 0;
    #pragma unroll
    for (int i = 0; i < 2; ++i) {
        int q = i*768 + tid;
        int cq = q >> 1, sq = q & 1;
        goff[i]   = q << 4;
        ldsoff[i] = (sq ? 3 : 0)*HPITCH + cq;
        if (sq) onemask |= (1<<i);      // s=1 carries only batch 3
    }

    char* pb[2];
    pb[0] = hbuf + (size_t)(0*NBG + bg)*BGBYTES;
    pb[1] = hbuf + (size_t)(1*NBG + bg)*BGBYTES;

    const float* xq = xp + (size_t)batch*SEQT*D3 + col;

    f32x4 ch[2];

#define ISSUE_POLLS(pbx)                                                 \
    {                                                                    \
        _Pragma("unroll")                                                \
        for (int k = 0; k < 2; ++k) {                                    \
            const f32x4* ap = (const f32x4*)((pbx) + goff[k]);           \
            asm volatile("global_load_dwordx4 %0, %1, off sc0 sc1"       \
                         : "=v"(ch[k]) : "v"(ap));                       \
        }                                                                \
    }

#define WAIT_FILL(pbx, hb0, tt)                                          \
    {                                                                    \
        asm volatile("s_waitcnt vmcnt(0)" ::: "memory");                 \
        __builtin_amdgcn_sched_barrier(0);                               \
        int need = 3;                                                    \
        _Pragma("unroll")                                                \
        for (int k = 0; k < 2; ++k)                                      \
            if (__float_as_int(ch[k].w) == (tt)) need &= ~(1<<k);        \
        while (need) {                                                   \
            _Pragma("unroll")                                            \
            for (int k = 0; k < 2; ++k)                                  \
                if (need & (1<<k)) {                                     \
                    const f32x4* ap = (const f32x4*)((pbx) + goff[k]);   \
                    asm volatile("global_load_dwordx4 %0, %1, off sc0 sc1"\
                                 : "=v"(ch[k]) : "v"(ap));               \
                }                                                        \
            asm volatile("s_waitcnt vmcnt(0)" ::: "memory");             \
            __builtin_amdgcn_sched_barrier(0);                           \
            _Pragma("unroll")                                            \
            for (int k = 0; k < 2; ++k)                                  \
                if ((need & (1<<k)) && __float_as_int(ch[k].w) == (tt))  \
                    need &= ~(1<<k);                                     \
            if (need) __builtin_amdgcn_s_sleep(1);                       \
        }                                                                \
        _Pragma("unroll")                                                \
        for (int k = 0; k < 2; ++k) {                                    \
            (hb0)[ldsoff[k]] = ch[k].x;                                  \
            if (!((onemask >> k) & 1)) {                                 \
                (hb0)[ldsoff[k] + HPITCH]   = ch[k].y;                   \
                (hb0)[ldsoff[k] + 2*HPITCH] = ch[k].z;                   \
            }                                                            \
        }                                                                \
    }

#define GRU_GATES(xr, xz, xn, ar, az, an)                                \
    {                                                                    \
        float rg = 1.f / (1.f + expf(-((xr) + (ar) + bhr)));             \
        float zg = 1.f / (1.f + expf(-((xz) + (az) + bhz)));             \
        float ng = tanhf((xn) + rg * ((an) + bhn));                      \
        hold = (1.f - zg) * ng + zg * hold;                              \
    }

    // publish: lanes 0..3 build this wave's 2 cols x 2 subs.
    // lane p: col gp=(p>>1)&1, sub sq=p&1.
    //   sq0 chunk = [h(b0),h(b1),h(b2),tag]  (src lanes gp*32+{0,8,16})
    //   sq1 chunk = [h(b3),  -,   -, tag]    (src lane  gp*32+24)
#define PUBLISH(pbx, tt)                                                 \
    {                                                                    \
        int gp = (lane >> 1) & 1;                                        \
        int sq = lane & 1;                                               \
        float q0 = __shfl(hold, gp*32 + (sq ? 24 : 0));                  \
        float q1 = __shfl(hold, gp*32 + 8);                              \
        float q2 = __shfl(hold, gp*32 + 16);                             \
        if (lane < 4) {                                                  \
            f32x4 val;                                                   \
            val.x = q0; val.y = q1; val.z = q2;                          \
            val.w = __int_as_float((tt) + 1);                            \
            int colp = jb*CPW + w*2 + gp;                                \
            f32x4* ap = (f32x4*)((pbx) + (size_t)(colp*2 + sq)*16);      \
            asm volatile("global_store_dwordx4 %0, %1, off sc0 sc1"      \
                         :: "v"(ap), "v"(val) : "memory");               \
        }                                                                \
        if ((c32 & 7) == 0)                                              \
            states[(size_t)(batch*SEQT + (tt))*DIM + col] = hold;        \
    }

    float hold = 0.f;

    // ---------------- prologue: t = 0 (h = 0 -> recurrent accums 0)
    float xr = xq[0], xz = xq[DIM], xn = xq[2*DIM];
    GRU_GATES(xr, xz, xn, 0.f, 0.f, 0.f);
    PUBLISH(pb[0], 0);
    ISSUE_POLLS(pb[0]);                  // speculative sweep for t=1
    // xp(1) prefetch
    float xrn = xq[(size_t)D3], xzn = xq[(size_t)D3 + DIM],
          xnn = xq[(size_t)D3 + 2*DIM];

    // ---------------- main loop
    for (int t = 1; t < SEQT; ++t) {
        float* hb0 = &h_lds[t & 1][0][0];
        WAIT_FILL(pb[(t-1)&1], hb0, t);
        // rotate xp regs; issue next prefetch (drained by t+1's sweep)
        xr = xrn; xz = xzn; xn = xnn;
        if (t + 1 < SEQT) {
            xrn = xq[(size_t)(t+1)*D3];
            xzn = xq[(size_t)(t+1)*D3 + DIM];
            xnn = xq[(size_t)(t+1)*D3 + 2*DIM];
        }
        __syncthreads();

        // ---- partial dots: 4 batches x 3 gates, k-slice c32*4+m*128
        float v[12];
        #pragma unroll
        for (int i = 0; i < 12; ++i) v[i] = 0.f;
        const float* hk = hb0 + c32*4;
        #pragma unroll
        for (int bb = 0; bb < 4; ++bb) {
            const float* hr = hk + bb*HPITCH;
            #pragma unroll
            for (int m = 0; m < 6; ++m) {
                f32x4 h4 = *(const f32x4*)(hr + m*128);
                v[bb*3+0] += DOT4(h4, w4[0][m]);
                v[bb*3+1] += DOT4(h4, w4[1][m]);
                v[bb*3+2] += DOT4(h4, w4[2][m]);
            }
        }
        // ---- reduce: bits 4,3 -> batch (scatter), 2,1,0 butterfly
        #pragma unroll
        for (int i = 0; i < 6; ++i) {
            float send = (c32 & 16) ? v[i] : v[i+6];
            float keep = (c32 & 16) ? v[i+6] : v[i];
            v[i] = keep + __shfl_xor(send, 16);
        }
        #pragma unroll
        for (int i = 0; i < 3; ++i) {
            float send = (c32 & 8) ? v[i] : v[i+3];
            float keep = (c32 & 8) ? v[i+3] : v[i];
            v[i] = keep + __shfl_xor(send, 8);
        }
        #pragma unroll
        for (int i = 0; i < 3; ++i) v[i] += __shfl_xor(v[i], 4);
        #pragma unroll
        for (int i = 0; i < 3; ++i) v[i] += __shfl_xor(v[i], 2);
        #pragma unroll
        for (int i = 0; i < 3; ++i) v[i] += __shfl_xor(v[i], 1);

        GRU_GATES(xr, xz, xn, v[0], v[1], v[2]);
        PUBLISH(pb[t&1], t);
        if (t + 1 < SEQT)
            ISSUE_POLLS(pb[t&1]);        // speculative sweep for t+1
    }
#undef ISSUE_POLLS
#undef WAIT_FILL
#undef GRU_GATES
#undef PUBLISH
}

// =========================================================
// K3: probs[r] = sigmoid(dot(states[r], w_act) + b_act)
// =========================================================
__global__ __launch_bounds__(256, 4) void k_probs(
    const float* __restrict__ states, const float* __restrict__ w_act,
    const float* __restrict__ b_act, float* __restrict__ probs,
    float* __restrict__ out_probs)
{
    int row  = blockIdx.x*4 + (threadIdx.x >> 6);
    int lane = threadIdx.x & 63;
    const float* sr = states + (size_t)row * DIM;
    float s = 0.f;
    #pragma unroll
    for (int i = 0; i < 3; ++i) {
        float4 v = *(const float4*)(sr + i*256 + lane*4);
        float4 w = *(const float4*)(w_act + i*256 + lane*4);
        s += v.x*w.x + v.y*w.y + v.z*w.z + v.w*w.w;
    }
    #pragma unroll
    for (int off = 32; off > 0; off >>= 1) s += __shfl_xor(s, off);
    if (lane == 0) {
        float pv = 1.f / (1.f + expf(-(s + b_act[0])));
        probs[row]     = pv;
        out_probs[row] = pv;
    }
}

// =========================================================
// K4: per-batch halting scan -> weights, segment bounds, n_segs
// =========================================================
__global__ void k_scan(const float* __restrict__ probs, float* __restrict__ weights,
                       int* __restrict__ seg_start, int* __restrict__ seg_end,
                       int* __restrict__ n_segs)
{
    int b = threadIdx.x;
    if (b >= BATCH) return;
    float acc = 0.f;
    int s = 0, start = 0;
    for (int t0 = 0; t0 < SEQT; t0 += 4) {
        float4 p4 = *(const float4*)(probs + b*SEQT + t0);
        float pv[4] = {p4.x, p4.y, p4.z, p4.w};
        #pragma unroll
        for (int k = 0; k < 4; ++k) {
            int t = t0 + k;
            float pp = pv[k];
            acc += pp;
            float w = pp;
            if (acc > VTHRESH) {
                w = pp - (acc - 1.0f);
                seg_start[b*SEQT + s] = start;
                seg_end[b*SEQT + s]   = t;
                s++; start = t + 1; acc = 0.f;
            }
            weights[b*SEQT + t] = w;
        }
    }
    n_segs[b] = s;
}

// =========================================================
// K5: embs row (b,s) = sum_{t in segment s} weights[b,t]*states[b,t,:]
// =========================================================
__global__ __launch_bounds__(256, 4) void k_embs(
    const float* __restrict__ states, const float* __restrict__ weights,
    const int* __restrict__ seg_start, const int* __restrict__ seg_end,
    const int* __restrict__ n_segs, float* __restrict__ out)
{
    int r = blockIdx.x;
    int b = r / SEQT;
    int s = r - b*SEQT;
    int tid = threadIdx.x;
    float a0 = 0.f, a1 = 0.f, a2 = 0.f;
    if (s < n_segs[b]) {
        int st = seg_start[r], en = seg_end[r];
        for (int t = st; t <= en; ++t) {
            float w = weights[b*SEQT + t];
            const float* sp = states + (size_t)(b*SEQT + t) * DIM;
            a0 += w * sp[tid];
            a1 += w * sp[tid + 256];
            a2 += w * sp[tid + 512];
        }
    }
    float* o = out + (size_t)r * DIM;
    o[tid]       = a0;
    o[tid + 256] = a1;
    o[tid + 512] = a2;
}

__global__ void k_init(float* hb) {
    int i = blockIdx.x * 256 + threadIdx.x;
    if (i < INIT_FLOATS) hb[i] = 0.f;
}

extern "C" void kernel_launch(void* const* d_in, const int* in_sizes, int n_in,
                              void* d_out, int out_size, void* d_ws, size_t ws_size,
                              hipStream_t stream)
{
    const int*   sent  = (const int*)d_in[0];
    const float* emb   = (const float*)d_in[1];
    const float* w_ih  = (const float*)d_in[2];
    const float* w_hh  = (const float*)d_in[3];
    const float* b_ih  = (const float*)d_in[4];
    const float* b_hh  = (const float*)d_in[5];
    const float* w_act = (const float*)d_in[6];
    const float* b_act = (const float*)d_in[7];
    float* out = (float*)d_out;

    char* ws = (char*)d_ws;
    float* xp      = (float*)(ws + OFF_XP);
    float* states  = (float*)(ws + OFF_ST);
    float* probs   = (float*)(ws + OFF_PR);
    float* weights = (float*)(ws + OFF_WT);
    int*   sstart  = (int*)(ws + OFF_SS);
    int*   send    = (int*)(ws + OFF_SE);
    int*   nsegs   = (int*)(ws + OFF_NS);
    char*  hbuf    = (char*)(ws + OFF_HB);

    k_init<<<384, 256, 0, stream>>>((float*)hbuf);
    k_xp<<<dim3(96, 18), 256, 0, stream>>>(sent, emb, w_ih, b_ih, xp);
    k_gru<<<256, 768, 0, stream>>>(w_hh, b_hh, xp, states, hbuf);
    k_probs<<<NROWS/4, 256, 0, stream>>>(states, w_act, b_act, probs,
                                         out + (size_t)NROWS * DIM);
    k_scan<<<1, 64, 0, stream>>>(probs, weights, sstart, send, nsegs);
    k_embs<<<NROWS, 256, 0, stream>>>(states, weights, sstart, send, nsegs, out);
}

// Round 7
// 2197.341 us; speedup vs baseline: 1.6857x; 1.0620x over previous
//
#include <hip/hip_runtime.h>
#include <math.h>

#define BATCH 32
#define SEQT 384
#define DIM 768
#define D3 2304
#define NROWS (BATCH*SEQT)      // 12288
#define VTHRESH 0.95f

typedef float  f32x4 __attribute__((ext_vector_type(4)));

// ---------------- workspace layout (bytes) ----------------
#define OFF_XP   ((size_t)0)
#define SZ_XP    ((size_t)NROWS * D3 * 4)            // 113,246,208
#define OFF_ST   (OFF_XP + SZ_XP)
#define SZ_ST    ((size_t)NROWS * DIM * 4)           // 37,748,736
#define OFF_PR   (OFF_ST + SZ_ST)
#define SZ_PR    ((size_t)NROWS * 4)
#define OFF_WT   (OFF_PR + SZ_PR)
#define OFF_SS   (OFF_WT + SZ_PR)
#define OFF_SE   (OFF_SS + SZ_PR)
#define OFF_NS   (OFF_SE + SZ_PR)
#define OFF_HB   (OFF_NS + 256)
// hbuf: 2 parity x 8 bg x 768 cols x 2 chunks x 16B = 393,216 B
// chunk layout per col: s0=[b0,b1,b2,tag]  s1=[b3,-,-,tag]
#define NBG 8               // batch groups (4 batches each)
#define BPG 4               // batches per group
#define WPB 32              // WGs per bg
#define CPW 24              // cols per WG
#define BGBYTES ((size_t)(DIM * 2 * 16))     // 24,576
#define SZ_HB   ((size_t)2 * NBG * BGBYTES)  // 393,216
#define INIT_FLOATS (SZ_HB/4)                // 98,304

#define DOT4(a,b) ((a).x*(b).x + (a).y*(b).y + (a).z*(b).z + (a).w*(b).w)

// fast transcendentals: v_exp_f32 / v_rcp_f32 (1 ulp — negligible vs
// the existing 2.4e-4 fp32-ordering absmax).
__device__ __forceinline__ float fexp2(float x) {
    float r; asm("v_exp_f32 %0, %1" : "=v"(r) : "v"(x)); return r;
}
__device__ __forceinline__ float frcp(float x) {
    float r; asm("v_rcp_f32 %0, %1" : "=v"(r) : "v"(x)); return r;
}
#define LOG2E 1.44269504f

// =========================================================
// K1: xp[m][n] = sum_k emb[sent[m]][k] * w_ih[n][k] + b_ih[n]
// =========================================================
__global__ __launch_bounds__(256, 2) void k_xp(
    const int* __restrict__ sent, const float* __restrict__ emb,
    const float* __restrict__ w_ih, const float* __restrict__ b_ih,
    float* __restrict__ xp)
{
    __shared__ float As[16][132];
    __shared__ float Bs[16][132];
    const int tid = threadIdx.x;
    const int mt = blockIdx.x, nt = blockIdx.y;
    const int tx = tid & 15, ty = tid >> 4;
    const int lm = tid >> 2;          // 0..63
    const int lk = (tid & 3) << 2;    // 0,4,8,12

    const long arow0 = (long)sent[mt*128 + lm] * DIM;
    const long arow1 = (long)sent[mt*128 + lm + 64] * DIM;
    const float* b0p = w_ih + (size_t)(nt*128 + lm) * DIM;
    const float* b1p = w_ih + (size_t)(nt*128 + lm + 64) * DIM;

    float acc[8][8];
    #pragma unroll
    for (int i = 0; i < 8; ++i)
        #pragma unroll
        for (int j = 0; j < 8; ++j) acc[i][j] = 0.f;

    for (int k0 = 0; k0 < DIM; k0 += 16) {
        float4 a0 = *(const float4*)(emb + arow0 + k0 + lk);
        float4 a1 = *(const float4*)(emb + arow1 + k0 + lk);
        float4 b0 = *(const float4*)(b0p + k0 + lk);
        float4 b1 = *(const float4*)(b1p + k0 + lk);
        __syncthreads();
        As[lk+0][lm] = a0.x; As[lk+1][lm] = a0.y; As[lk+2][lm] = a0.z; As[lk+3][lm] = a0.w;
        As[lk+0][lm+64] = a1.x; As[lk+1][lm+64] = a1.y; As[lk+2][lm+64] = a1.z; As[lk+3][lm+64] = a1.w;
        Bs[lk+0][lm] = b0.x; Bs[lk+1][lm] = b0.y; Bs[lk+2][lm] = b0.z; Bs[lk+3][lm] = b0.w;
        Bs[lk+0][lm+64] = b1.x; Bs[lk+1][lm+64] = b1.y; Bs[lk+2][lm+64] = b1.z; Bs[lk+3][lm+64] = b1.w;
        __syncthreads();
        #pragma unroll
        for (int k = 0; k < 16; ++k) {
            float4 av0 = *(const float4*)&As[k][ty*8];
            float4 av1 = *(const float4*)&As[k][ty*8+4];
            float4 bv0 = *(const float4*)&Bs[k][tx*8];
            float4 bv1 = *(const float4*)&Bs[k][tx*8+4];
            float a[8] = {av0.x,av0.y,av0.z,av0.w,av1.x,av1.y,av1.z,av1.w};
            float b[8] = {bv0.x,bv0.y,bv0.z,bv0.w,bv1.x,bv1.y,bv1.z,bv1.w};
            #pragma unroll
            for (int i = 0; i < 8; ++i)
                #pragma unroll
                for (int j = 0; j < 8; ++j)
                    acc[i][j] += a[i]*b[j];
        }
    }

    const int m0 = mt*128 + ty*8;
    const int n0 = nt*128 + tx*8;
    float4 bi0 = *(const float4*)(b_ih + n0);
    float4 bi1 = *(const float4*)(b_ih + n0 + 4);
    #pragma unroll
    for (int i = 0; i < 8; ++i) {
        float4 v0, v1;
        v0.x = acc[i][0] + bi0.x; v0.y = acc[i][1] + bi0.y;
        v0.z = acc[i][2] + bi0.z; v0.w = acc[i][3] + bi0.w;
        v1.x = acc[i][4] + bi1.x; v1.y = acc[i][5] + bi1.y;
        v1.z = acc[i][6] + bi1.z; v1.w = acc[i][7] + bi1.w;
        *(float4*)(xp + (size_t)(m0+i)*D3 + n0)     = v0;
        *(float4*)(xp + (size_t)(m0+i)*D3 + n0 + 4) = v1;
    }
}

// =========================================================
// K2: persistent GRU recurrence, v11 — issue-trim + split-k pipeline.
//   R6 post-mortem: VALU-busy time invariant at 1.13ms (now 63% of
//   1.78ms); VGPR_Count=72 yet w4 alone is 72 regs -> compiler
//   REMATERIALIZES the weight loads inside the t-loop (per-step L2
//   re-reads + issue). Three fixes on v10's proven structure:
//   1. w4 loaded via inline-asm opaque loads (+vmcnt+sched_barrier):
//      cannot be rematerialized -> truly resident (~130 VGPR <=170
//      keeps 3 waves/SIMD).
//   2. fast gates: sigmoid = rcp(1+exp2(-x*log2e)) (4 inst),
//      tanh = 1-2*rcp(1+exp2(2x*log2e)) (5 inst) vs libm ~50-70.
//   3. split-k two-phase: ch[0] = lower 384 cols, ch[1] = upper.
//      Wait only on ch[0] tag; fill lower; barrier A; dots m=0..2
//      while stale-ch[1] re-load flies; validate/fill upper;
//      barrier B; dots m=3..5. Upper-half producer tail hides under
//      lower-half compute. xp(t+1) prefetch issued after barrier B
//      (flies across upper dots + publish; not caught by phase-U
//      vmcnt).
//   Protocol (tagged 1-RT chunks, per-wave immediate publish,
//   2-deep parity) unchanged from v9/v10.
// =========================================================
#define HPITCH 772

__global__ __launch_bounds__(768, 1) void k_gru(
    const float* __restrict__ w_hh, const float* __restrict__ b_hh,
    const float* __restrict__ xp, float* __restrict__ states,
    char* __restrict__ hbuf)
{
    __shared__ float h_lds[2][BPG][HPITCH];   // 24,704 B

    const int tid = threadIdx.x;
    const int jb  = blockIdx.x & 31;      // WG within bg
    const int bg  = blockIdx.x >> 5;      // 0..7
    const int w    = tid >> 6;            // wave 0..11
    const int lane = tid & 63;
    const int half = lane >> 5;           // which of the wave's 2 cols
    const int c32  = lane & 31;
    const int col  = jb*CPW + w*2 + half;
    const int bloc = (c32 >> 3) & 3;      // batch-in-group 0..3
    const int batch = bg*BPG + bloc;

    // weights: asm-opaque loads -> compiler cannot rematerialize;
    // w4 stays in VGPRs for the whole kernel (fix for VGPR=72 reload).
    f32x4 w4[3][6];
    #pragma unroll
    for (int g3 = 0; g3 < 3; ++g3) {
        const float* wr = w_hh + (size_t)(g3*DIM + col)*DIM + c32*4;
        #pragma unroll
        for (int m = 0; m < 6; ++m) {
            const f32x4* ap = (const f32x4*)(wr + m*128);
            asm volatile("global_load_dwordx4 %0, %1, off"
                         : "=v"(w4[g3][m]) : "v"(ap));
        }
    }
    asm volatile("s_waitcnt vmcnt(0)" ::: "memory");
    __builtin_amdgcn_sched_barrier(0);

    const float bhr = b_hh[col];
    const float bhz = b_hh[DIM + col];
    const float bhn = b_hh[2*DIM + col];

    // consumer chunk assignment: i=0 -> lower col (tid>>1), i=1 -> upper
    int goff[2], ldsoff[2], onemask = 0;
    #pragma unroll
    for (int i = 0; i < 2; ++i) {
        int q = i*768 + tid;
        int cq = q >> 1, sq = q & 1;
        goff[i]   = q << 4;
        ldsoff[i] = (sq ? 3 : 0)*HPITCH + cq;
        if (sq) onemask |= (1<<i);      // s=1 carries only batch 3
    }

    char* pb[2];
    pb[0] = hbuf + (size_t)(0*NBG + bg)*BGBYTES;
    pb[1] = hbuf + (size_t)(1*NBG + bg)*BGBYTES;

    const float* xq = xp + (size_t)batch*SEQT*D3 + col;

    f32x4 ch[2];

#define ISSUE_POLLS(pbx)                                                 \
    {                                                                    \
        _Pragma("unroll")                                                \
        for (int k = 0; k < 2; ++k) {                                    \
            const f32x4* ap = (const f32x4*)((pbx) + goff[k]);           \
            asm volatile("global_load_dwordx4 %0, %1, off sc0 sc1"       \
                         : "=v"(ch[k]) : "v"(ap));                       \
        }                                                                \
    }

#define GRU_GATES(xr, xz, xn, ar, az, an)                                \
    {                                                                    \
        float rg = frcp(1.f + fexp2(-LOG2E*((xr) + (ar) + bhr)));        \
        float zg = frcp(1.f + fexp2(-LOG2E*((xz) + (az) + bhz)));        \
        float sn = (xn) + rg * ((an) + bhn);                             \
        float ng = 1.f - 2.f*frcp(1.f + fexp2(2.f*LOG2E*sn));            \
        hold = (1.f - zg) * ng + zg * hold;                              \
    }

    // publish: lanes 0..3 build this wave's 2 cols x 2 subs.
#define PUBLISH(pbx, tt)                                                 \
    {                                                                    \
        int gp = (lane >> 1) & 1;                                        \
        int sq = lane & 1;                                               \
        float q0 = __shfl(hold, gp*32 + (sq ? 24 : 0));                  \
        float q1 = __shfl(hold, gp*32 + 8);                              \
        float q2 = __shfl(hold, gp*32 + 16);                             \
        if (lane < 4) {                                                  \
            f32x4 val;                                                   \
            val.x = q0; val.y = q1; val.z = q2;                          \
            val.w = __int_as_float((tt) + 1);                            \
            int colp = jb*CPW + w*2 + gp;                                \
            f32x4* ap = (f32x4*)((pbx) + (size_t)(colp*2 + sq)*16);      \
            asm volatile("global_store_dwordx4 %0, %1, off sc0 sc1"      \
                         :: "v"(ap), "v"(val) : "memory");               \
        }                                                                \
        if ((c32 & 7) == 0)                                              \
            states[(size_t)(batch*SEQT + (tt))*DIM + col] = hold;        \
    }

    float hold = 0.f;

    // ---------------- prologue: t = 0 (h = 0 -> recurrent accums 0)
    float xr = xq[0], xz = xq[DIM], xn = xq[2*DIM];
    GRU_GATES(xr, xz, xn, 0.f, 0.f, 0.f);
    PUBLISH(pb[0], 0);
    ISSUE_POLLS(pb[0]);                  // speculative sweep for t=1
    float xrn = xq[(size_t)D3], xzn = xq[(size_t)D3 + DIM],
          xnn = xq[(size_t)D3 + 2*DIM];

    // ---------------- main loop
    for (int t = 1; t < SEQT; ++t) {
        float* hb0 = &h_lds[t & 1][0][0];
        const char* pbx = pb[(t-1)&1];

        // ===== phase L: wait lower chunk; opportunistic upper =====
        asm volatile("s_waitcnt vmcnt(0)" ::: "memory");
        __builtin_amdgcn_sched_barrier(0);
        bool up_ok = (__float_as_int(ch[1].w) == t);
        while (__float_as_int(ch[0].w) != t) {
            __builtin_amdgcn_s_sleep(1);
            {
                const f32x4* a0 = (const f32x4*)(pbx + goff[0]);
                asm volatile("global_load_dwordx4 %0, %1, off sc0 sc1"
                             : "=v"(ch[0]) : "v"(a0));
            }
            if (!up_ok) {
                const f32x4* a1 = (const f32x4*)(pbx + goff[1]);
                asm volatile("global_load_dwordx4 %0, %1, off sc0 sc1"
                             : "=v"(ch[1]) : "v"(a1));
            }
            asm volatile("s_waitcnt vmcnt(0)" ::: "memory");
            __builtin_amdgcn_sched_barrier(0);
            if (!up_ok) up_ok = (__float_as_int(ch[1].w) == t);
        }
        // fill lower; upper now if valid, else launch one re-load
        hb0[ldsoff[0]] = ch[0].x;
        if (!(onemask & 1)) {
            hb0[ldsoff[0] + HPITCH]   = ch[0].y;
            hb0[ldsoff[0] + 2*HPITCH] = ch[0].z;
        }
        if (up_ok) {
            hb0[ldsoff[1]] = ch[1].x;
            if (!(onemask & 2)) {
                hb0[ldsoff[1] + HPITCH]   = ch[1].y;
                hb0[ldsoff[1] + 2*HPITCH] = ch[1].z;
            }
        } else {
            const f32x4* a1 = (const f32x4*)(pbx + goff[1]);
            asm volatile("global_load_dwordx4 %0, %1, off sc0 sc1"
                         : "=v"(ch[1]) : "v"(a1));
        }
        xr = xrn; xz = xzn; xn = xnn;
        __syncthreads();                       // barrier A

        // ---- dots lower half: m = 0..2 (k in [0,384))
        float v[12];
        #pragma unroll
        for (int i = 0; i < 12; ++i) v[i] = 0.f;
        const float* hk = hb0 + c32*4;
        #pragma unroll
        for (int bb = 0; bb < 4; ++bb) {
            const float* hr = hk + bb*HPITCH;
            #pragma unroll
            for (int m = 0; m < 3; ++m) {
                f32x4 h4 = *(const f32x4*)(hr + m*128);
                v[bb*3+0] += DOT4(h4, w4[0][m]);
                v[bb*3+1] += DOT4(h4, w4[1][m]);
                v[bb*3+2] += DOT4(h4, w4[2][m]);
            }
        }

        // ===== phase U: validate + fill upper (usually pre-filled) =====
        if (!up_ok) {
            asm volatile("s_waitcnt vmcnt(0)" ::: "memory");
            __builtin_amdgcn_sched_barrier(0);
            while (__float_as_int(ch[1].w) != t) {
                __builtin_amdgcn_s_sleep(1);
                const f32x4* a1 = (const f32x4*)(pbx + goff[1]);
                asm volatile("global_load_dwordx4 %0, %1, off sc0 sc1"
                             : "=v"(ch[1]) : "v"(a1));
                asm volatile("s_waitcnt vmcnt(0)" ::: "memory");
                __builtin_amdgcn_sched_barrier(0);
            }
            hb0[ldsoff[1]] = ch[1].x;
            if (!(onemask & 2)) {
                hb0[ldsoff[1] + HPITCH]   = ch[1].y;
                hb0[ldsoff[1] + 2*HPITCH] = ch[1].z;
            }
        }
        __syncthreads();                       // barrier B

        // xp(t+1) prefetch: flies across upper dots + publish
        if (t + 1 < SEQT) {
            xrn = xq[(size_t)(t+1)*D3];
            xzn = xq[(size_t)(t+1)*D3 + DIM];
            xnn = xq[(size_t)(t+1)*D3 + 2*DIM];
        }

        // ---- dots upper half: m = 3..5 (k in [384,768))
        #pragma unroll
        for (int bb = 0; bb < 4; ++bb) {
            const float* hr = hk + bb*HPITCH;
            #pragma unroll
            for (int m = 3; m < 6; ++m) {
                f32x4 h4 = *(const f32x4*)(hr + m*128);
                v[bb*3+0] += DOT4(h4, w4[0][m]);
                v[bb*3+1] += DOT4(h4, w4[1][m]);
                v[bb*3+2] += DOT4(h4, w4[2][m]);
            }
        }
        // ---- reduce: bits 4,3 -> batch (scatter), 2,1,0 butterfly
        #pragma unroll
        for (int i = 0; i < 6; ++i) {
            float send = (c32 & 16) ? v[i] : v[i+6];
            float keep = (c32 & 16) ? v[i+6] : v[i];
            v[i] = keep + __shfl_xor(send, 16);
        }
        #pragma unroll
        for (int i = 0; i < 3; ++i) {
            float send = (c32 & 8) ? v[i] : v[i+3];
            float keep = (c32 & 8) ? v[i+3] : v[i];
            v[i] = keep + __shfl_xor(send, 8);
        }
        #pragma unroll
        for (int i = 0; i < 3; ++i) v[i] += __shfl_xor(v[i], 4);
        #pragma unroll
        for (int i = 0; i < 3; ++i) v[i] += __shfl_xor(v[i], 2);
        #pragma unroll
        for (int i = 0; i < 3; ++i) v[i] += __shfl_xor(v[i], 1);

        GRU_GATES(xr, xz, xn, v[0], v[1], v[2]);
        PUBLISH(pb[t&1], t);
        if (t + 1 < SEQT)
            ISSUE_POLLS(pb[t&1]);        // speculative sweep for t+1
    }
#undef ISSUE_POLLS
#undef GRU_GATES
#undef PUBLISH
}

// =========================================================
// K3: probs[r] = sigmoid(dot(states[r], w_act) + b_act)
// =========================================================
__global__ __launch_bounds__(256, 4) void k_probs(
    const float* __restrict__ states, const float* __restrict__ w_act,
    const float* __restrict__ b_act, float* __restrict__ probs,
    float* __restrict__ out_probs)
{
    int row  = blockIdx.x*4 + (threadIdx.x >> 6);
    int lane = threadIdx.x & 63;
    const float* sr = states + (size_t)row * DIM;
    float s = 0.f;
    #pragma unroll
    for (int i = 0; i < 3; ++i) {
        float4 v = *(const float4*)(sr + i*256 + lane*4);
        float4 w = *(const float4*)(w_act + i*256 + lane*4);
        s += v.x*w.x + v.y*w.y + v.z*w.z + v.w*w.w;
    }
    #pragma unroll
    for (int off = 32; off > 0; off >>= 1) s += __shfl_xor(s, off);
    if (lane == 0) {
        float pv = 1.f / (1.f + expf(-(s + b_act[0])));
        probs[row]     = pv;
        out_probs[row] = pv;
    }
}

// =========================================================
// K4: per-batch halting scan -> weights, segment bounds, n_segs
// =========================================================
__global__ void k_scan(const float* __restrict__ probs, float* __restrict__ weights,
                       int* __restrict__ seg_start, int* __restrict__ seg_end,
                       int* __restrict__ n_segs)
{
    int b = threadIdx.x;
    if (b >= BATCH) return;
    float acc = 0.f;
    int s = 0, start = 0;
    for (int t0 = 0; t0 < SEQT; t0 += 4) {
        float4 p4 = *(const float4*)(probs + b*SEQT + t0);
        float pv[4] = {p4.x, p4.y, p4.z, p4.w};
        #pragma unroll
        for (int k = 0; k < 4; ++k) {
            int t = t0 + k;
            float pp = pv[k];
            acc += pp;
            float w = pp;
            if (acc > VTHRESH) {
                w = pp - (acc - 1.0f);
                seg_start[b*SEQT + s] = start;
                seg_end[b*SEQT + s]   = t;
                s++; start = t + 1; acc = 0.f;
            }
            weights[b*SEQT + t] = w;
        }
    }
    n_segs[b] = s;
}

// =========================================================
// K5: embs row (b,s) = sum_{t in segment s} weights[b,t]*states[b,t,:]
// =========================================================
__global__ __launch_bounds__(256, 4) void k_embs(
    const float* __restrict__ states, const float* __restrict__ weights,
    const int* __restrict__ seg_start, const int* __restrict__ seg_end,
    const int* __restrict__ n_segs, float* __restrict__ out)
{
    int r = blockIdx.x;
    int b = r / SEQT;
    int s = r - b*SEQT;
    int tid = threadIdx.x;
    float a0 = 0.f, a1 = 0.f, a2 = 0.f;
    if (s < n_segs[b]) {
        int st = seg_start[r], en = seg_end[r];
        for (int t = st; t <= en; ++t) {
            float w = weights[b*SEQT + t];
            const float* sp = states + (size_t)(b*SEQT + t) * DIM;
            a0 += w * sp[tid];
            a1 += w * sp[tid + 256];
            a2 += w * sp[tid + 512];
        }
    }
    float* o = out + (size_t)r * DIM;
    o[tid]       = a0;
    o[tid + 256] = a1;
    o[tid + 512] = a2;
}

__global__ void k_init(float* hb) {
    int i = blockIdx.x * 256 + threadIdx.x;
    if (i < INIT_FLOATS) hb[i] = 0.f;
}

extern "C" void kernel_launch(void* const* d_in, const int* in_sizes, int n_in,
                              void* d_out, int out_size, void* d_ws, size_t ws_size,
                              hipStream_t stream)
{
    const int*   sent  = (const int*)d_in[0];
    const float* emb   = (const float*)d_in[1];
    const float* w_ih  = (const float*)d_in[2];
    const float* w_hh  = (const float*)d_in[3];
    const float* b_ih  = (const float*)d_in[4];
    const float* b_hh  = (const float*)d_in[5];
    const float* w_act = (const float*)d_in[6];
    const float* b_act = (const float*)d_in[7];
    float* out = (float*)d_out;

    char* ws = (char*)d_ws;
    float* xp      = (float*)(ws + OFF_XP);
    float* states  = (float*)(ws + OFF_ST);
    float* probs   = (float*)(ws + OFF_PR);
    float* weights = (float*)(ws + OFF_WT);
    int*   sstart  = (int*)(ws + OFF_SS);
    int*   send    = (int*)(ws + OFF_SE);
    int*   nsegs   = (int*)(ws + OFF_NS);
    char*  hbuf    = (char*)(ws + OFF_HB);

    k_init<<<384, 256, 0, stream>>>((float*)hbuf);
    k_xp<<<dim3(96, 18), 256, 0, stream>>>(sent, emb, w_ih, b_ih, xp);
    k_gru<<<256, 768, 0, stream>>>(w_hh, b_hh, xp, states, hbuf);
    k_probs<<<NROWS/4, 256, 0, stream>>>(states, w_act, b_act, probs,
                                         out + (size_t)NROWS * DIM);
    k_scan<<<1, 64, 0, stream>>>(probs, weights, sstart, send, nsegs);
    k_embs<<<NROWS, 256, 0, stream>>>(states, weights, sstart, send, nsegs, out);
}